// Round 20
// baseline (171.451 us; speedup 1.0000x reference)
//
#include <hip/hip_runtime.h>
#include <hip/hip_bf16.h>
#include <hip/hip_fp16.h>

// Problem constants
#define BQ    256
#define NKEY  100000
#define DD    512
#define AD    256
#define CD    100
#define KSEL  32
#define KB    64            // keys per K1 block
#define NB    1563          // ceil(NKEY/KB)
#define CPQ   (NB*12)       // cand entries per query = 18756

// selection params (round-17-validated)
#define NPART 8             // k2a blocks per query
#define WTOP  12            // per-wave top list emitted by k2a
#define NC2   (NPART*4*WTOP)  // 384 rescore candidates per query
#define TLA   6             // per-lane list depth in k2a

typedef __attribute__((ext_vector_type(8))) short  short8_t;
typedef __attribute__((ext_vector_type(8))) __bf16 bf16x8;
typedef __attribute__((ext_vector_type(4))) float  f32x4;

__device__ __forceinline__ unsigned short f2bf(float x) {
  unsigned int u = __float_as_uint(x);
  return (unsigned short)((u + 0x7FFFu + ((u >> 16) & 1u)) >> 16);  // RTNE
}
__device__ __forceinline__ unsigned short f2bf_n(float x) {
  __bf16 h = (__bf16)x;                 // native cvt, pairs into v_cvt_pk_bf16_f32
  return __builtin_bit_cast(unsigned short, h);
}
__device__ __forceinline__ float bf2f(unsigned short h) {
  return __uint_as_float(((unsigned int)h) << 16);
}
__device__ __forceinline__ f32x4 mfma_bf16(short8_t a, short8_t b, f32x4 c) {
  return __builtin_amdgcn_mfma_f32_16x16x32_bf16(
      __builtin_bit_cast(bf16x8, a), __builtin_bit_cast(bf16x8, b), c, 0, 0, 0);
}
__device__ __forceinline__ float fast_tanh(float x) {
  x = fminf(fmaxf(x, -15.f), 15.f);
  float e = __expf(2.f * x);
  return (e - 1.f) * __builtin_amdgcn_rcpf(e + 1.f);
}

template<int T>
__device__ __forceinline__ void topk_insert(float (&v)[T], int (&ix)[T], float val, int idx) {
  if (val <= v[T-1]) return;
  v[T-1] = val; ix[T-1] = idx;
  #pragma unroll
  for (int j = T-1; j > 0; --j) {
    bool sw = v[j] > v[j-1];
    float tv = sw ? v[j] : v[j-1];  float uv = sw ? v[j-1] : v[j];
    int   ti = sw ? ix[j] : ix[j-1]; int  ui = sw ? ix[j-1] : ix[j];
    v[j-1] = tv; v[j] = uv; ix[j-1] = ti; ix[j] = ui;
  }
}

// ---------------- K0 (merged): blocks 0..255 = query prep; blocks 256..767 = Wm fragmenting ----------------
__global__ __launch_bounds__(256) void k0_prep(const float* __restrict__ qfeat,
                                               const float* __restrict__ Wm,
                                               float* __restrict__ qr,
                                               unsigned short* __restrict__ qf,
                                               float* __restrict__ qn,
                                               unsigned short* __restrict__ wmf) {
  int b = blockIdx.x, t = threadIdx.x;
  if (b >= BQ) {
    int i = (b - BQ)*256 + t;   // i = d*256 + a, 131072 total
    int d = i >> 8, a = i & 255;
    wmf[(((a>>4)*64 + (d>>3))*16 + (a&15))*8 + (d&7)] = f2bf(Wm[i]);
    return;
  }
  float s = 0.f;
  #pragma unroll
  for (int p = 0; p < 2; ++p) {
    int k = t + p*256;
    float v = qfeat[b*DD + k];
    v = v > 0.f ? v : 0.f;
    qr[b*DD + k] = v;
    qf[(((b>>4)*64 + (k>>3))*16 + (b&15))*8 + (k&7)] = f2bf(v);
    s += v*v;
  }
  __shared__ float red[4];
  #pragma unroll
  for (int st = 1; st < 64; st <<= 1) s += __shfl_xor(s, st, 64);
  if ((t & 63) == 0) red[t>>6] = s;
  __syncthreads();
  if (t == 0) qn[b] = sqrtf(red[0]+red[1]+red[2]+red[3]);
}

// ---------------- K1 (fused): blocks 0..NB-1 = coarse GEMM; blocks NB.. = qq GEMM ----------------
__global__ __launch_bounds__(256) void k1_fused(const float* __restrict__ keys,
                                                const unsigned short* __restrict__ qf,
                                                unsigned int* __restrict__ cand,
                                                const float* __restrict__ Wq,
                                                const float* __restrict__ bq,
                                                const float* __restrict__ bm,
                                                float* __restrict__ qq) {
  __shared__ __align__(16) char shmem[16640];   // aliased: k1 uses 8.4KB, qq path 16KB
  int b = blockIdx.x, t = threadIdx.x;
  int w = t >> 6, l = t & 63, g = l >> 4, c = l & 15;
  const short8_t* qf8 = (const short8_t*)qf;

  if (b >= NB) {
    // ---- k_qq path ----
    unsigned short* wb = (unsigned short*)shmem;   // 16 KB
    int bb = b - NB;
    int bn = bb & 15, rg = bb >> 4;
    #pragma unroll
    for (int i = 0; i < 32; ++i) {
      int d = i*16 + (t>>4); int a = t & 15;
      wb[((d>>3)*16 + a)*8 + (d&7)] = f2bf(Wq[d*AD + bn*16 + a]);
    }
    __syncthreads();
    const short8_t* wb8 = (const short8_t*)wb;
    f32x4 acc = (f32x4){0.f,0.f,0.f,0.f};
    int M = rg*4 + w;
    for (int kt = 0; kt < 16; ++kt) {
      short8_t bfr = wb8[(kt*4 + g)*16 + c];
      short8_t afr = qf8[(M*64 + kt*4 + g)*16 + c];
      acc = mfma_bf16(afr, bfr, acc);
    }
    int col = bn*16 + c;
    float bias = bq[col] + bm[col];
    #pragma unroll
    for (int r = 0; r < 4; ++r)
      qq[(M*16 + g*4 + r)*AD + col] = acc[r] + bias;
    return;
  }

  // ---- k1 path ----
  short8_t* Abf8 = (short8_t*)shmem;             // 8 KB
  float* invkn = (float*)(shmem + 8192);         // 256 B
  int kb0 = b*KB;

  f32x4 acc[4][4];   // [key m-tile][query n-tile]
  #pragma unroll
  for (int m = 0; m < 4; ++m)
    #pragma unroll
    for (int n = 0; n < 4; ++n) acc[m][n] = (f32x4){0.f,0.f,0.f,0.f};

  // staging assignment: thread t stages rows r1,r2 dim-granule gb
  int r1 = t >> 3, gb = t & 7;
  int r2 = 32 + r1;
  int swz = gb ^ (r1 & 7);                 // r2&7 == r1&7
  int row1 = kb0 + r1; row1 = row1 < NKEY ? row1 : NKEY-1;
  int row2 = kb0 + r2; row2 = row2 < NKEY ? row2 : NKEY-1;
  const float* src1 = keys + (size_t)row1*DD + gb*8;
  const float* src2 = keys + (size_t)row2*DD + gb*8;
  float ksq1 = 0.f, ksq2 = 0.f;

  // prologue: B(0) [8 instr], then G(0) -> Ge [4], G(1) -> Go [4]
  short8_t Bcur[2][4];
  #pragma unroll
  for (int kt = 0; kt < 2; ++kt)
    #pragma unroll
    for (int n = 0; n < 4; ++n)
      Bcur[kt][n] = qf8[((w*4 + n)*64 + kt*4 + g)*16 + c];
  __builtin_amdgcn_sched_barrier(0);
  float4 Ge[4], Go[4];
  Ge[0] = *(const float4*)(src1);      Ge[1] = *(const float4*)(src1 + 4);
  Ge[2] = *(const float4*)(src2);      Ge[3] = *(const float4*)(src2 + 4);
  __builtin_amdgcn_sched_barrier(0);
  Go[0] = *(const float4*)(src1 + 64); Go[1] = *(const float4*)(src1 + 68);
  Go[2] = *(const float4*)(src2 + 64); Go[3] = *(const float4*)(src2 + 68);

  auto body = [&](int ks8, float4 (&Gc)[4]) {
    if (ks8 < 7) asm volatile("s_waitcnt vmcnt(4)" ::: "memory");
    else         asm volatile("s_waitcnt vmcnt(0)" ::: "memory");
    // norms + cvt from registers
    ksq1 += Gc[0].x*Gc[0].x + Gc[0].y*Gc[0].y + Gc[0].z*Gc[0].z + Gc[0].w*Gc[0].w
          + Gc[1].x*Gc[1].x + Gc[1].y*Gc[1].y + Gc[1].z*Gc[1].z + Gc[1].w*Gc[1].w;
    ksq2 += Gc[2].x*Gc[2].x + Gc[2].y*Gc[2].y + Gc[2].z*Gc[2].z + Gc[2].w*Gc[2].w
          + Gc[3].x*Gc[3].x + Gc[3].y*Gc[3].y + Gc[3].z*Gc[3].z + Gc[3].w*Gc[3].w;
    short8_t w1, w2;
    w1[0] = (short)f2bf_n(Gc[0].x); w1[1] = (short)f2bf_n(Gc[0].y);
    w1[2] = (short)f2bf_n(Gc[0].z); w1[3] = (short)f2bf_n(Gc[0].w);
    w1[4] = (short)f2bf_n(Gc[1].x); w1[5] = (short)f2bf_n(Gc[1].y);
    w1[6] = (short)f2bf_n(Gc[1].z); w1[7] = (short)f2bf_n(Gc[1].w);
    w2[0] = (short)f2bf_n(Gc[2].x); w2[1] = (short)f2bf_n(Gc[2].y);
    w2[2] = (short)f2bf_n(Gc[2].z); w2[3] = (short)f2bf_n(Gc[2].w);
    w2[4] = (short)f2bf_n(Gc[3].x); w2[5] = (short)f2bf_n(Gc[3].y);
    w2[6] = (short)f2bf_n(Gc[3].z); w2[7] = (short)f2bf_n(Gc[3].w);
    __builtin_amdgcn_s_barrier();                       // prev-iter LDS reads done
    Abf8[r1*8 + swz] = w1;
    Abf8[r2*8 + swz] = w2;
    short8_t Bnxt[2][4];
    if (ks8 < 7) {
      #pragma unroll
      for (int kt = 0; kt < 2; ++kt)
        #pragma unroll
        for (int n = 0; n < 4; ++n)
          Bnxt[kt][n] = qf8[((w*4 + n)*64 + (ks8+1)*8 + kt*4 + g)*16 + c];
    }
    __builtin_amdgcn_sched_barrier(0);                  // pin B(t+1) before G(t+2)
    if (ks8 < 6) {
      Gc[0] = *(const float4*)(src1 + (ks8+2)*64);
      Gc[1] = *(const float4*)(src1 + (ks8+2)*64 + 4);
      Gc[2] = *(const float4*)(src2 + (ks8+2)*64);
      Gc[3] = *(const float4*)(src2 + (ks8+2)*64 + 4);
    }
    asm volatile("s_waitcnt lgkmcnt(0)" ::: "memory");  // own ds_writes visible
    __builtin_amdgcn_s_barrier();
    __builtin_amdgcn_sched_barrier(0);
    int p = c & 7;
    __builtin_amdgcn_s_setprio(1);                      // T5: favor MFMA-entering waves
    #pragma unroll
    for (int kt = 0; kt < 2; ++kt) {
      #pragma unroll
      for (int m = 0; m < 4; ++m) {
        short8_t A = Abf8[(m*16 + c)*8 + ((kt*4 + g) ^ p)];
        #pragma unroll
        for (int n = 0; n < 4; ++n) acc[m][n] = mfma_bf16(A, Bcur[kt][n], acc[m][n]);
      }
    }
    __builtin_amdgcn_s_setprio(0);
    if (ks8 < 7) {
      #pragma unroll
      for (int kt = 0; kt < 2; ++kt)
        #pragma unroll
        for (int n = 0; n < 4; ++n) Bcur[kt][n] = Bnxt[kt][n];
    }
  };

  #pragma unroll
  for (int ks8 = 0; ks8 < 8; ++ks8) {
    if (ks8 & 1) body(ks8, Go);
    else         body(ks8, Ge);
  }

  // norms: reduce over the 8 gb-threads of each row (lanes differ in bits 0..2)
  ksq1 += __shfl_xor(ksq1, 1, 64); ksq1 += __shfl_xor(ksq1, 2, 64); ksq1 += __shfl_xor(ksq1, 4, 64);
  ksq2 += __shfl_xor(ksq2, 1, 64); ksq2 += __shfl_xor(ksq2, 2, 64); ksq2 += __shfl_xor(ksq2, 4, 64);
  if ((t & 7) == 0) {
    invkn[r1] = ksq1 > 0.f ? rsqrtf(ksq1) : 0.f;
    invkn[r2] = ksq2 > 0.f ? rsqrtf(ksq2) : 0.f;
  }
  __syncthreads();

  float ikv[16];
  #pragma unroll
  for (int m = 0; m < 4; ++m)
    #pragma unroll
    for (int r = 0; r < 4; ++r) ikv[m*4 + r] = invkn[m*16 + g*4 + r];

  // per-lane branchless top-3 of the lane's 16 keys, per query column
  #pragma unroll
  for (int n = 0; n < 4; ++n) {
    float v1 = -3.0e38f, v2 = -3.0e38f, v3 = -3.0e38f;
    int   i1 = 0, i2 = 0, i3 = 0;
    #pragma unroll
    for (int m = 0; m < 4; ++m)
      #pragma unroll
      for (int r = 0; r < 4; ++r) {
        int lid = m*16 + g*4 + r;
        bool valid = (kb0 + lid) < NKEY;
        float v = valid ? acc[m][n][r] * ikv[m*4 + r] : -3.0e38f;
        bool gt1 = v > v1, gt2 = v > v2, gt3 = v > v3;
        v3 = gt2 ? v2 : (gt3 ? v : v3);  i3 = gt2 ? i2 : (gt3 ? lid : i3);
        v2 = gt1 ? v1 : (gt2 ? v : v2);  i2 = gt1 ? i1 : (gt2 ? lid : i2);
        v1 = gt1 ? v  : v1;              i1 = gt1 ? lid : i1;
      }
    int q = w*64 + n*16 + c;
    unsigned int base = ((unsigned int)q*NB + (unsigned int)b)*12u + (unsigned int)g*3u;
    cand[base + 0] = ((unsigned int)__half_as_ushort(__float2half(v1)) << 16) | (unsigned int)i1;
    cand[base + 1] = ((unsigned int)__half_as_ushort(__float2half(v2)) << 16) | (unsigned int)i2;
    cand[base + 2] = ((unsigned int)__half_as_ushort(__float2half(v3)) << 16) | (unsigned int)i3;
  }
}

// ---------------- K2a: candidate reduce + EXACT fp32 rescore (8 blocks/query, 32 waves/CU) ----------------
__global__ __launch_bounds__(256) void k2a_reduce(const unsigned int* __restrict__ cand,
                                                  const float* __restrict__ qr,
                                                  const float* __restrict__ qn,
                                                  const float* __restrict__ keys,
                                                  float* __restrict__ wtopv,
                                                  int* __restrict__ wtopi) {
  int bid = blockIdx.x;
  int q = bid >> 3, p = bid & 7;
  int t = threadIdx.x, w = t >> 6, l = t & 63;
  const unsigned int* cq = cand + (size_t)q * CPQ;

  const int PER_PART = (CPQ + NPART - 1) / NPART;   // 2345
  const int PER_WAVE = (PER_PART + 3) / 4;          // 587
  int pbase = p * PER_PART;
  int start = pbase + w * PER_WAVE;
  int end   = pbase + PER_PART;
  if (start + PER_WAVE < end) end = start + PER_WAVE;
  if (end > CPQ) end = CPQ;

  float v[TLA]; int ix[TLA];
  #pragma unroll
  for (int j = 0; j < TLA; ++j) { v[j] = -INFINITY; ix[j] = -1; }
  for (int i = start + l; i < end; i += 64) {
    unsigned int pk = cq[i];
    float val = __half2float(__ushort_as_half((unsigned short)(pk >> 16)));
    int bb = i / 12;                       // compiler magic-mul
    int idx = (bb << 6) | (int)(pk & 63u);
    topk_insert<TLA>(v, ix, val, idx);
  }

  // wave merge: exact wave top-WTOP; winning index is wave-uniform -> keep in regs
  int idxs[WTOP];
  for (int it = 0; it < WTOP; ++it) {
    float bv = v[0]; int bx = ix[0]; int bl = l;
    #pragma unroll
    for (int sft = 1; sft < 64; sft <<= 1) {
      float ov = __shfl_xor(bv, sft, 64);
      int  oxx = __shfl_xor(bx, sft, 64);
      int  ol  = __shfl_xor(bl, sft, 64);
      bool take = (ov > bv) || (ov == bv && ol < bl);
      if (take) { bv = ov; bx = oxx; bl = ol; }
    }
    idxs[it] = bx;
    if (l == bl) {
      #pragma unroll
      for (int j = 0; j < TLA-1; ++j) { v[j] = v[j+1]; ix[j] = ix[j+1]; }
      v[TLA-1] = -INFINITY; ix[TLA-1] = -1;
    }
  }

  // exact fp32 rescore of this wave's 12 candidates (2-deep row pipeline; lane = 8-dim slice)
  const float4* q4 = (const float4*)(qr + (size_t)q*DD + l*8);
  float4 qa0 = q4[0], qa1 = q4[1];
  float qnv = qn[q];
  int obase = (q * NPART + p) * 4 * WTOP + w * WTOP;

  int nidx = idxs[0];
  const float4* kr = (const float4*)(keys + (size_t)((nidx < 0 || nidx >= NKEY) ? 0 : nidx)*DD + l*8);
  float4 k0v = kr[0], k1v = kr[1];
  for (int j = 0; j < WTOP; ++j) {
    int curidx = idxs[j];
    bool bad = (curidx < 0) || (curidx >= NKEY);
    float4 c0 = k0v, c1 = k1v;
    if (j + 1 < WTOP) {
      nidx = idxs[j+1];
      kr = (const float4*)(keys + (size_t)((nidx < 0 || nidx >= NKEY) ? 0 : nidx)*DD + l*8);
      k0v = kr[0]; k1v = kr[1];
    }
    float dot = qa0.x*c0.x + qa0.y*c0.y + qa0.z*c0.z + qa0.w*c0.w
              + qa1.x*c1.x + qa1.y*c1.y + qa1.z*c1.z + qa1.w*c1.w;
    float ks  = c0.x*c0.x + c0.y*c0.y + c0.z*c0.z + c0.w*c0.w
              + c1.x*c1.x + c1.y*c1.y + c1.z*c1.z + c1.w*c1.w;
    #pragma unroll
    for (int sft = 1; sft < 64; sft <<= 1) {
      dot += __shfl_xor(dot, sft, 64);
      ks  += __shfl_xor(ks,  sft, 64);
    }
    if (l == 0) {
      float den = fmaxf(qnv * sqrtf(ks), 1e-8f);
      wtopv[obase + j] = bad ? -1e30f : dot/den;
      wtopi[obase + j] = bad ? 0 : curidx;
    }
  }
}

// ---------------- K23ab: top-32 of precomputed exact sims (384) -> gather -> attention -> attf ----------------
__global__ __launch_bounds__(256) void k23ab(const float* __restrict__ wtopv,
                                             const int* __restrict__ wtopi,
                                             const float* __restrict__ keys,
                                             const float* __restrict__ qq,
                                             const unsigned short* __restrict__ wmf,
                                             const float* __restrict__ Ws,
                                             const float* __restrict__ bsc,
                                             unsigned short* __restrict__ attf) {
  int q = blockIdx.x, t = threadIdx.x, w = t >> 6, l = t & 63, g = l >> 4, c = l & 15;
  __shared__ float simx[NC2];
  __shared__ int   sidx[NC2];
  __shared__ int   fl[KSEL];
  __shared__ float qqb[256];
  __shared__ float wsl[256];
  __shared__ unsigned short knnb[32*520];
  __shared__ float spart[4][32];
  __shared__ float wexp[32];

  qqb[t] = qq[q*AD + t];
  wsl[t] = Ws[t];
  for (int i = t; i < NC2; i += 256) {
    simx[i] = wtopv[q*NC2 + i];
    int idx = wtopi[q*NC2 + i];
    sidx[i] = (idx < 0 || idx >= NKEY) ? 0 : idx;
  }
  __syncthreads();

  // wave 0: exact top-32 of 384, tie-break value desc then index asc (lax.top_k)
  if (w == 0) {
    float a[6]; int id[6];
    #pragma unroll
    for (int j = 0; j < 6; ++j) { a[j] = simx[j*64 + l]; id[j] = sidx[j*64 + l]; }
    for (int it = 0; it < KSEL; ++it) {
      float bv = a[0]; int bx = id[0]; int bslot = 0;
      #pragma unroll
      for (int j = 1; j < 6; ++j) {
        bool take = (a[j] > bv) || (a[j] == bv && id[j] < bx);
        bv = take ? a[j] : bv; bx = take ? id[j] : bx; bslot = take ? j : bslot;
      }
      int bl = l;
      #pragma unroll
      for (int sft = 1; sft < 64; sft <<= 1) {
        float ov = __shfl_xor(bv, sft, 64);
        int  oxx = __shfl_xor(bx, sft, 64);
        int  ol  = __shfl_xor(bl, sft, 64);
        bool take = (ov > bv) || (ov == bv && oxx < bx);
        if (take) { bv = ov; bx = oxx; bl = ol; }
      }
      if (l == 0) fl[it] = bx;
      if (l == bl) {
        #pragma unroll
        for (int j = 0; j < 6; ++j) if (j == bslot) a[j] = -INFINITY;
      }
    }
  }
  __syncthreads();

  // gather knn (bf16), MFMA knn@Wm, tanh/score/softmax, attended -> attf
  #pragma unroll 4
  for (int rr = 0; rr < 32; rr += 2) {
    int r = rr + (t >> 7);
    int row = fl[r];
    int d4 = t & 127;
    float4 v = *(const float4*)(keys + (size_t)row*DD + d4*4);
    ushort4 h; h.x = f2bf_n(v.x); h.y = f2bf_n(v.y); h.z = f2bf_n(v.z); h.w = f2bf_n(v.w);
    *(ushort4*)&knnb[r*520 + d4*4] = h;
  }
  __syncthreads();

  f32x4 acc[2][4];
  #pragma unroll
  for (int m = 0; m < 2; ++m)
    #pragma unroll
    for (int n = 0; n < 4; ++n) acc[m][n] = (f32x4){0.f,0.f,0.f,0.f};
  const short8_t* wmf8 = (const short8_t*)wmf;
  for (int ks = 0; ks < 16; ++ks) {
    short8_t af[2], bf[4];
    #pragma unroll
    for (int m = 0; m < 2; ++m) af[m] = *(const short8_t*)&knnb[(m*16 + c)*520 + ks*32 + g*8];
    #pragma unroll
    for (int n = 0; n < 4; ++n) bf[n] = wmf8[((w*4 + n)*64 + ks*4 + g)*16 + c];
    #pragma unroll
    for (int m = 0; m < 2; ++m)
      #pragma unroll
      for (int n = 0; n < 4; ++n) acc[m][n] = mfma_bf16(af[m], bf[n], acc[m][n]);
  }

  float p[8] = {0.f,0.f,0.f,0.f,0.f,0.f,0.f,0.f};
  #pragma unroll
  for (int n = 0; n < 4; ++n) {
    int a = w*64 + n*16 + c;
    float qv = qqb[a], wv = wsl[a];
    #pragma unroll
    for (int m = 0; m < 2; ++m)
      #pragma unroll
      for (int r = 0; r < 4; ++r)
        p[m*4 + r] += fast_tanh(acc[m][n][r] + qv) * wv;
  }
  #pragma unroll
  for (int sft = 1; sft < 16; sft <<= 1)
    #pragma unroll
    for (int i = 0; i < 8; ++i) p[i] += __shfl_xor(p[i], sft, 64);
  if (c == 0) {
    #pragma unroll
    for (int m = 0; m < 2; ++m)
      #pragma unroll
      for (int r = 0; r < 4; ++r) spart[w][m*16 + g*4 + r] = p[m*4 + r];
  }
  __syncthreads();

  if (t < 32) {
    float s = spart[0][t] + spart[1][t] + spart[2][t] + spart[3][t] + bsc[0];
    float mx = s;
    #pragma unroll
    for (int sft = 1; sft < 32; sft <<= 1) mx = fmaxf(mx, __shfl_xor(mx, sft, 64));
    float e = __expf(s - mx);
    float su = e;
    #pragma unroll
    for (int sft = 1; sft < 32; sft <<= 1) su += __shfl_xor(su, sft, 64);
    wexp[t] = e / su;
  }
  __syncthreads();

  #pragma unroll
  for (int pth = 0; pth < 2; ++pth) {
    int d = t + pth*256;
    float s = 0.f;
    #pragma unroll
    for (int k = 0; k < 32; ++k) s += wexp[k] * bf2f(knnb[k*520 + d]);
    attf[(((q>>4)*64 + (d>>3))*16 + (q&15))*8 + (d&7)] = f2bf(s);
  }
}

// ---------------- K3b: out = [q, attended] @ Wc + bc  (28 blocks: 7 col-tiles x 4 row-groups) ----------------
__global__ __launch_bounds__(256) void k3b_cls(const float* __restrict__ Wc,
                                               const unsigned short* __restrict__ qf,
                                               const unsigned short* __restrict__ attf,
                                               const float* __restrict__ bc,
                                               float* __restrict__ out) {
  __shared__ unsigned short wb[128*16*8];   // 32 KB
  int bn = blockIdx.x % 7, rg = blockIdx.x / 7;
  int t = threadIdx.x;
  int w = t >> 6, l = t & 63, g = l >> 4, c = l & 15;
  #pragma unroll
  for (int i = 0; i < 64; ++i) {
    int d = i*16 + (t>>4); int a = t & 15;
    int col = bn*16 + a;
    float vv = (col < CD) ? Wc[d*CD + col] : 0.f;
    wb[((d>>3)*16 + a)*8 + (d&7)] = f2bf(vv);
  }
  __syncthreads();
  const short8_t* qf8 = (const short8_t*)qf;
  const short8_t* af8 = (const short8_t*)attf;
  const short8_t* wb8 = (const short8_t*)wb;
  int M = rg*4 + w;                         // this wave's 16-row tile (0..15)
  f32x4 acc = (f32x4){0.f,0.f,0.f,0.f};
  for (int kt = 0; kt < 32; ++kt) {
    short8_t bfr = wb8[(kt*4 + g)*16 + c];
    const short8_t* asrc = (kt < 16) ? qf8 : af8;
    int kbase = (kt & 15)*4 + g;
    short8_t afr = asrc[(M*64 + kbase)*16 + c];
    acc = mfma_bf16(afr, bfr, acc);
  }
  int col = bn*16 + c;
  if (col < CD) {
    float bias = bc[col];
    #pragma unroll
    for (int r = 0; r < 4; ++r)
      out[(M*16 + g*4 + r)*CD + col] = acc[r] + bias;
  }
}

// ---------------- launch ----------------
extern "C" void kernel_launch(void* const* d_in, const int* in_sizes, int n_in,
                              void* d_out, int out_size, void* d_ws, size_t ws_size,
                              hipStream_t stream) {
  const float* qfeat = (const float*)d_in[0];
  const float* keys  = (const float*)d_in[1];
  const float* Wq    = (const float*)d_in[2];
  const float* bq    = (const float*)d_in[3];
  const float* Wm    = (const float*)d_in[4];
  const float* bm    = (const float*)d_in[5];
  const float* Ws    = (const float*)d_in[6];
  const float* bsc   = (const float*)d_in[7];
  const float* Wc    = (const float*)d_in[8];
  const float* bc    = (const float*)d_in[9];
  float* out = (float*)d_out;

  char* ws = (char*)d_ws;
  unsigned short* qf   = (unsigned short*)(ws + 0);          // 262144 B
  float*          qr   = (float*)(ws + 262144);              // 524288 B
  float*          qn   = (float*)(ws + 786432);              // 1024 B
  unsigned short* wmf  = (unsigned short*)(ws + 787456);     // 262144 B
  float*          qq   = (float*)(ws + 1049600);             // 262144 B
  unsigned short* attf = (unsigned short*)(ws + 1311744);    // 262144 B
  float*          wtopv= (float*)(ws + 1573888);             // 393216 B
  int*            wtopi= (int*)(ws + 1967104);               // 393216 B
  unsigned int*   cand = (unsigned int*)(ws + 2360320);      // 19203072 B

  k0_prep   <<<768,      256, 0, stream>>>(qfeat, Wm, qr, qf, qn, wmf);
  k1_fused  <<<NB + 64,  256, 0, stream>>>(keys, qf, cand, Wq, bq, bm, qq);
  k2a_reduce<<<BQ*NPART, 256, 0, stream>>>(cand, qr, qn, keys, wtopv, wtopi);
  k23ab     <<<BQ,       256, 0, stream>>>(wtopv, wtopi, keys, qq, wmf, Ws, bsc, attf);
  k3b_cls   <<<28,       256, 0, stream>>>(Wc, qf, attf, bc, out);
}

// Round 21
// 167.351 us; speedup vs baseline: 1.0245x; 1.0245x over previous
//
#include <hip/hip_runtime.h>
#include <hip/hip_bf16.h>
#include <hip/hip_fp16.h>

// Problem constants
#define BQ    256
#define NKEY  100000
#define DD    512
#define AD    256
#define CD    100
#define KSEL  32
#define KB    64            // keys per K1 block
#define NB    1563          // ceil(NKEY/KB)
#define CPQ   (NB*12)       // cand entries per query = 18756

// selection params (round-17-validated)
#define NPART 8             // k2a blocks per query
#define WTOP  12            // per-wave top list emitted by k2a
#define NC2   (NPART*4*WTOP)  // 384 rescore candidates per query
#define TLA   6             // per-lane list depth in k2a

typedef __attribute__((ext_vector_type(8))) short  short8_t;
typedef __attribute__((ext_vector_type(8))) __bf16 bf16x8;
typedef __attribute__((ext_vector_type(4))) float  f32x4;

__device__ __forceinline__ unsigned short f2bf(float x) {
  unsigned int u = __float_as_uint(x);
  return (unsigned short)((u + 0x7FFFu + ((u >> 16) & 1u)) >> 16);  // RTNE
}
__device__ __forceinline__ unsigned short f2bf_n(float x) {
  __bf16 h = (__bf16)x;                 // native cvt, pairs into v_cvt_pk_bf16_f32
  return __builtin_bit_cast(unsigned short, h);
}
__device__ __forceinline__ float bf2f(unsigned short h) {
  return __uint_as_float(((unsigned int)h) << 16);
}
__device__ __forceinline__ f32x4 mfma_bf16(short8_t a, short8_t b, f32x4 c) {
  return __builtin_amdgcn_mfma_f32_16x16x32_bf16(
      __builtin_bit_cast(bf16x8, a), __builtin_bit_cast(bf16x8, b), c, 0, 0, 0);
}
__device__ __forceinline__ float fast_tanh(float x) {
  x = fminf(fmaxf(x, -15.f), 15.f);
  float e = __expf(2.f * x);
  return (e - 1.f) * __builtin_amdgcn_rcpf(e + 1.f);
}

template<int T>
__device__ __forceinline__ void topk_insert(float (&v)[T], int (&ix)[T], float val, int idx) {
  if (val <= v[T-1]) return;
  v[T-1] = val; ix[T-1] = idx;
  #pragma unroll
  for (int j = T-1; j > 0; --j) {
    bool sw = v[j] > v[j-1];
    float tv = sw ? v[j] : v[j-1];  float uv = sw ? v[j-1] : v[j];
    int   ti = sw ? ix[j] : ix[j-1]; int  ui = sw ? ix[j-1] : ix[j];
    v[j-1] = tv; v[j] = uv; ix[j-1] = ti; ix[j] = ui;
  }
}

// ---------------- K0 (merged): blocks 0..255 = query prep; blocks 256..767 = Wm fragmenting ----------------
__global__ __launch_bounds__(256) void k0_prep(const float* __restrict__ qfeat,
                                               const float* __restrict__ Wm,
                                               float* __restrict__ qr,
                                               unsigned short* __restrict__ qf,
                                               float* __restrict__ qn,
                                               unsigned short* __restrict__ wmf) {
  int b = blockIdx.x, t = threadIdx.x;
  if (b >= BQ) {
    int i = (b - BQ)*256 + t;   // i = d*256 + a, 131072 total
    int d = i >> 8, a = i & 255;
    wmf[(((a>>4)*64 + (d>>3))*16 + (a&15))*8 + (d&7)] = f2bf(Wm[i]);
    return;
  }
  float s = 0.f;
  #pragma unroll
  for (int p = 0; p < 2; ++p) {
    int k = t + p*256;
    float v = qfeat[b*DD + k];
    v = v > 0.f ? v : 0.f;
    qr[b*DD + k] = v;
    qf[(((b>>4)*64 + (k>>3))*16 + (b&15))*8 + (k&7)] = f2bf(v);
    s += v*v;
  }
  __shared__ float red[4];
  #pragma unroll
  for (int st = 1; st < 64; st <<= 1) s += __shfl_xor(s, st, 64);
  if ((t & 63) == 0) red[t>>6] = s;
  __syncthreads();
  if (t == 0) qn[b] = sqrtf(red[0]+red[1]+red[2]+red[3]);
}

// ---------------- K1 (fused): blocks 0..NB-1 = coarse GEMM; blocks NB.. = qq GEMM ----------------
__global__ __launch_bounds__(256) void k1_fused(const float* __restrict__ keys,
                                                const unsigned short* __restrict__ qf,
                                                unsigned int* __restrict__ cand,
                                                const float* __restrict__ Wq,
                                                const float* __restrict__ bq,
                                                const float* __restrict__ bm,
                                                float* __restrict__ qq) {
  __shared__ __align__(16) char shmem[16640];   // aliased: k1 uses 8.4KB, qq path 16KB
  int b = blockIdx.x, t = threadIdx.x;
  int w = t >> 6, l = t & 63, g = l >> 4, c = l & 15;
  const short8_t* qf8 = (const short8_t*)qf;

  if (b >= NB) {
    // ---- k_qq path ----
    unsigned short* wb = (unsigned short*)shmem;   // 16 KB
    int bb = b - NB;
    int bn = bb & 15, rg = bb >> 4;
    #pragma unroll
    for (int i = 0; i < 32; ++i) {
      int d = i*16 + (t>>4); int a = t & 15;
      wb[((d>>3)*16 + a)*8 + (d&7)] = f2bf(Wq[d*AD + bn*16 + a]);
    }
    __syncthreads();
    const short8_t* wb8 = (const short8_t*)wb;
    f32x4 acc = (f32x4){0.f,0.f,0.f,0.f};
    int M = rg*4 + w;
    for (int kt = 0; kt < 16; ++kt) {
      short8_t bfr = wb8[(kt*4 + g)*16 + c];
      short8_t afr = qf8[(M*64 + kt*4 + g)*16 + c];
      acc = mfma_bf16(afr, bfr, acc);
    }
    int col = bn*16 + c;
    float bias = bq[col] + bm[col];
    #pragma unroll
    for (int r = 0; r < 4; ++r)
      qq[(M*16 + g*4 + r)*AD + col] = acc[r] + bias;
    return;
  }

  // ---- k1 path ----
  short8_t* Abf8 = (short8_t*)shmem;             // 8 KB
  float* invkn = (float*)(shmem + 8192);         // 256 B
  int kb0 = b*KB;

  f32x4 acc[4][4];   // [key m-tile][query n-tile]
  #pragma unroll
  for (int m = 0; m < 4; ++m)
    #pragma unroll
    for (int n = 0; n < 4; ++n) acc[m][n] = (f32x4){0.f,0.f,0.f,0.f};

  // staging assignment: thread t stages rows r1,r2 dim-granule gb
  int r1 = t >> 3, gb = t & 7;
  int r2 = 32 + r1;
  int swz = gb ^ (r1 & 7);                 // r2&7 == r1&7
  int row1 = kb0 + r1; row1 = row1 < NKEY ? row1 : NKEY-1;
  int row2 = kb0 + r2; row2 = row2 < NKEY ? row2 : NKEY-1;
  const float* src1 = keys + (size_t)row1*DD + gb*8;
  const float* src2 = keys + (size_t)row2*DD + gb*8;
  float ksq1 = 0.f, ksq2 = 0.f;

  // prologue: B(0) [8 instr], then G(0) -> Ge [4], G(1) -> Go [4]
  short8_t Bcur[2][4];
  #pragma unroll
  for (int kt = 0; kt < 2; ++kt)
    #pragma unroll
    for (int n = 0; n < 4; ++n)
      Bcur[kt][n] = qf8[((w*4 + n)*64 + kt*4 + g)*16 + c];
  __builtin_amdgcn_sched_barrier(0);
  float4 Ge[4], Go[4];
  Ge[0] = *(const float4*)(src1);      Ge[1] = *(const float4*)(src1 + 4);
  Ge[2] = *(const float4*)(src2);      Ge[3] = *(const float4*)(src2 + 4);
  __builtin_amdgcn_sched_barrier(0);
  Go[0] = *(const float4*)(src1 + 64); Go[1] = *(const float4*)(src1 + 68);
  Go[2] = *(const float4*)(src2 + 64); Go[3] = *(const float4*)(src2 + 68);

  auto body = [&](int ks8, float4 (&Gc)[4]) {
    if (ks8 < 7) asm volatile("s_waitcnt vmcnt(4)" ::: "memory");
    else         asm volatile("s_waitcnt vmcnt(0)" ::: "memory");
    // norms + cvt from registers
    ksq1 += Gc[0].x*Gc[0].x + Gc[0].y*Gc[0].y + Gc[0].z*Gc[0].z + Gc[0].w*Gc[0].w
          + Gc[1].x*Gc[1].x + Gc[1].y*Gc[1].y + Gc[1].z*Gc[1].z + Gc[1].w*Gc[1].w;
    ksq2 += Gc[2].x*Gc[2].x + Gc[2].y*Gc[2].y + Gc[2].z*Gc[2].z + Gc[2].w*Gc[2].w
          + Gc[3].x*Gc[3].x + Gc[3].y*Gc[3].y + Gc[3].z*Gc[3].z + Gc[3].w*Gc[3].w;
    short8_t w1, w2;
    w1[0] = (short)f2bf_n(Gc[0].x); w1[1] = (short)f2bf_n(Gc[0].y);
    w1[2] = (short)f2bf_n(Gc[0].z); w1[3] = (short)f2bf_n(Gc[0].w);
    w1[4] = (short)f2bf_n(Gc[1].x); w1[5] = (short)f2bf_n(Gc[1].y);
    w1[6] = (short)f2bf_n(Gc[1].z); w1[7] = (short)f2bf_n(Gc[1].w);
    w2[0] = (short)f2bf_n(Gc[2].x); w2[1] = (short)f2bf_n(Gc[2].y);
    w2[2] = (short)f2bf_n(Gc[2].z); w2[3] = (short)f2bf_n(Gc[2].w);
    w2[4] = (short)f2bf_n(Gc[3].x); w2[5] = (short)f2bf_n(Gc[3].y);
    w2[6] = (short)f2bf_n(Gc[3].z); w2[7] = (short)f2bf_n(Gc[3].w);
    __builtin_amdgcn_s_barrier();                       // prev-iter LDS reads done
    Abf8[r1*8 + swz] = w1;
    Abf8[r2*8 + swz] = w2;
    short8_t Bnxt[2][4];
    if (ks8 < 7) {
      #pragma unroll
      for (int kt = 0; kt < 2; ++kt)
        #pragma unroll
        for (int n = 0; n < 4; ++n)
          Bnxt[kt][n] = qf8[((w*4 + n)*64 + (ks8+1)*8 + kt*4 + g)*16 + c];
    }
    __builtin_amdgcn_sched_barrier(0);                  // pin B(t+1) before G(t+2)
    if (ks8 < 6) {
      Gc[0] = *(const float4*)(src1 + (ks8+2)*64);
      Gc[1] = *(const float4*)(src1 + (ks8+2)*64 + 4);
      Gc[2] = *(const float4*)(src2 + (ks8+2)*64);
      Gc[3] = *(const float4*)(src2 + (ks8+2)*64 + 4);
    }
    asm volatile("s_waitcnt lgkmcnt(0)" ::: "memory");  // own ds_writes visible
    __builtin_amdgcn_s_barrier();
    __builtin_amdgcn_sched_barrier(0);
    int p = c & 7;
    #pragma unroll
    for (int kt = 0; kt < 2; ++kt) {
      #pragma unroll
      for (int m = 0; m < 4; ++m) {
        short8_t A = Abf8[(m*16 + c)*8 + ((kt*4 + g) ^ p)];
        #pragma unroll
        for (int n = 0; n < 4; ++n) acc[m][n] = mfma_bf16(A, Bcur[kt][n], acc[m][n]);
      }
    }
    if (ks8 < 7) {
      #pragma unroll
      for (int kt = 0; kt < 2; ++kt)
        #pragma unroll
        for (int n = 0; n < 4; ++n) Bcur[kt][n] = Bnxt[kt][n];
    }
  };

  #pragma unroll
  for (int ks8 = 0; ks8 < 8; ++ks8) {
    if (ks8 & 1) body(ks8, Go);
    else         body(ks8, Ge);
  }

  // norms: reduce over the 8 gb-threads of each row (lanes differ in bits 0..2)
  ksq1 += __shfl_xor(ksq1, 1, 64); ksq1 += __shfl_xor(ksq1, 2, 64); ksq1 += __shfl_xor(ksq1, 4, 64);
  ksq2 += __shfl_xor(ksq2, 1, 64); ksq2 += __shfl_xor(ksq2, 2, 64); ksq2 += __shfl_xor(ksq2, 4, 64);
  if ((t & 7) == 0) {
    invkn[r1] = ksq1 > 0.f ? rsqrtf(ksq1) : 0.f;
    invkn[r2] = ksq2 > 0.f ? rsqrtf(ksq2) : 0.f;
  }
  __syncthreads();

  float ikv[16];
  #pragma unroll
  for (int m = 0; m < 4; ++m)
    #pragma unroll
    for (int r = 0; r < 4; ++r) ikv[m*4 + r] = invkn[m*16 + g*4 + r];

  // per-lane branchless top-3 of the lane's 16 keys, per query column
  #pragma unroll
  for (int n = 0; n < 4; ++n) {
    float v1 = -3.0e38f, v2 = -3.0e38f, v3 = -3.0e38f;
    int   i1 = 0, i2 = 0, i3 = 0;
    #pragma unroll
    for (int m = 0; m < 4; ++m)
      #pragma unroll
      for (int r = 0; r < 4; ++r) {
        int lid = m*16 + g*4 + r;
        bool valid = (kb0 + lid) < NKEY;
        float v = valid ? acc[m][n][r] * ikv[m*4 + r] : -3.0e38f;
        bool gt1 = v > v1, gt2 = v > v2, gt3 = v > v3;
        v3 = gt2 ? v2 : (gt3 ? v : v3);  i3 = gt2 ? i2 : (gt3 ? lid : i3);
        v2 = gt1 ? v1 : (gt2 ? v : v2);  i2 = gt1 ? i1 : (gt2 ? lid : i2);
        v1 = gt1 ? v  : v1;              i1 = gt1 ? lid : i1;
      }
    int q = w*64 + n*16 + c;
    unsigned int base = ((unsigned int)q*NB + (unsigned int)b)*12u + (unsigned int)g*3u;
    cand[base + 0] = ((unsigned int)__half_as_ushort(__float2half(v1)) << 16) | (unsigned int)i1;
    cand[base + 1] = ((unsigned int)__half_as_ushort(__float2half(v2)) << 16) | (unsigned int)i2;
    cand[base + 2] = ((unsigned int)__half_as_ushort(__float2half(v3)) << 16) | (unsigned int)i3;
  }
}

// ---------------- K2a: candidate reduce + EXACT fp32 rescore (8 blocks/query, 32 waves/CU) ----------------
__global__ __launch_bounds__(256) void k2a_reduce(const unsigned int* __restrict__ cand,
                                                  const float* __restrict__ qr,
                                                  const float* __restrict__ qn,
                                                  const float* __restrict__ keys,
                                                  float* __restrict__ wtopv,
                                                  int* __restrict__ wtopi) {
  int bid = blockIdx.x;
  int q = bid >> 3, p = bid & 7;
  int t = threadIdx.x, w = t >> 6, l = t & 63;
  const unsigned int* cq = cand + (size_t)q * CPQ;

  const int PER_PART = (CPQ + NPART - 1) / NPART;   // 2345
  const int PER_WAVE = (PER_PART + 3) / 4;          // 587
  int pbase = p * PER_PART;
  int start = pbase + w * PER_WAVE;
  int end   = pbase + PER_PART;
  if (start + PER_WAVE < end) end = start + PER_WAVE;
  if (end > CPQ) end = CPQ;

  float v[TLA]; int ix[TLA];
  #pragma unroll
  for (int j = 0; j < TLA; ++j) { v[j] = -INFINITY; ix[j] = -1; }
  for (int i = start + l; i < end; i += 64) {
    unsigned int pk = cq[i];
    float val = __half2float(__ushort_as_half((unsigned short)(pk >> 16)));
    int bb = i / 12;                       // compiler magic-mul
    int idx = (bb << 6) | (int)(pk & 63u);
    topk_insert<TLA>(v, ix, val, idx);
  }

  // wave merge: exact wave top-WTOP; winning index is wave-uniform -> keep in regs
  int idxs[WTOP];
  for (int it = 0; it < WTOP; ++it) {
    float bv = v[0]; int bx = ix[0]; int bl = l;
    #pragma unroll
    for (int sft = 1; sft < 64; sft <<= 1) {
      float ov = __shfl_xor(bv, sft, 64);
      int  oxx = __shfl_xor(bx, sft, 64);
      int  ol  = __shfl_xor(bl, sft, 64);
      bool take = (ov > bv) || (ov == bv && ol < bl);
      if (take) { bv = ov; bx = oxx; bl = ol; }
    }
    idxs[it] = bx;
    if (l == bl) {
      #pragma unroll
      for (int j = 0; j < TLA-1; ++j) { v[j] = v[j+1]; ix[j] = ix[j+1]; }
      v[TLA-1] = -INFINITY; ix[TLA-1] = -1;
    }
  }

  // exact fp32 rescore of this wave's 12 candidates (2-deep row pipeline; lane = 8-dim slice)
  const float4* q4 = (const float4*)(qr + (size_t)q*DD + l*8);
  float4 qa0 = q4[0], qa1 = q4[1];
  float qnv = qn[q];
  int obase = (q * NPART + p) * 4 * WTOP + w * WTOP;

  int nidx = idxs[0];
  const float4* kr = (const float4*)(keys + (size_t)((nidx < 0 || nidx >= NKEY) ? 0 : nidx)*DD + l*8);
  float4 k0v = kr[0], k1v = kr[1];
  for (int j = 0; j < WTOP; ++j) {
    int curidx = idxs[j];
    bool bad = (curidx < 0) || (curidx >= NKEY);
    float4 c0 = k0v, c1 = k1v;
    if (j + 1 < WTOP) {
      nidx = idxs[j+1];
      kr = (const float4*)(keys + (size_t)((nidx < 0 || nidx >= NKEY) ? 0 : nidx)*DD + l*8);
      k0v = kr[0]; k1v = kr[1];
    }
    float dot = qa0.x*c0.x + qa0.y*c0.y + qa0.z*c0.z + qa0.w*c0.w
              + qa1.x*c1.x + qa1.y*c1.y + qa1.z*c1.z + qa1.w*c1.w;
    float ks  = c0.x*c0.x + c0.y*c0.y + c0.z*c0.z + c0.w*c0.w
              + c1.x*c1.x + c1.y*c1.y + c1.z*c1.z + c1.w*c1.w;
    #pragma unroll
    for (int sft = 1; sft < 64; sft <<= 1) {
      dot += __shfl_xor(dot, sft, 64);
      ks  += __shfl_xor(ks,  sft, 64);
    }
    if (l == 0) {
      float den = fmaxf(qnv * sqrtf(ks), 1e-8f);
      wtopv[obase + j] = bad ? -1e30f : dot/den;
      wtopi[obase + j] = bad ? 0 : curidx;
    }
  }
}

// ---------------- K23ab (512 threads): top-32 select -> gather -> attention -> attf ----------------
__global__ __launch_bounds__(512) void k23ab(const float* __restrict__ wtopv,
                                             const int* __restrict__ wtopi,
                                             const float* __restrict__ keys,
                                             const float* __restrict__ qq,
                                             const unsigned short* __restrict__ wmf,
                                             const float* __restrict__ Ws,
                                             const float* __restrict__ bsc,
                                             unsigned short* __restrict__ attf) {
  int q = blockIdx.x, t = threadIdx.x, w = t >> 6, l = t & 63, g = l >> 4, c = l & 15;
  __shared__ float simx[NC2];
  __shared__ int   sidx[NC2];
  __shared__ int   fl[KSEL];
  __shared__ float qqb[256];
  __shared__ float wsl[256];
  __shared__ unsigned short knnb[32*520];
  __shared__ float spart[8][32];
  __shared__ float wexp[32];

  if (t < 256) {
    qqb[t] = qq[q*AD + t];
    wsl[t] = Ws[t];
  }
  for (int i = t; i < NC2; i += 512) {
    simx[i] = wtopv[q*NC2 + i];
    int idx = wtopi[q*NC2 + i];
    sidx[i] = (idx < 0 || idx >= NKEY) ? 0 : idx;
  }
  __syncthreads();

  // wave 0: exact top-32 of 384, tie-break value desc then index asc (lax.top_k)
  if (w == 0) {
    float a[6]; int id[6];
    #pragma unroll
    for (int j = 0; j < 6; ++j) { a[j] = simx[j*64 + l]; id[j] = sidx[j*64 + l]; }
    for (int it = 0; it < KSEL; ++it) {
      float bv = a[0]; int bx = id[0]; int bslot = 0;
      #pragma unroll
      for (int j = 1; j < 6; ++j) {
        bool take = (a[j] > bv) || (a[j] == bv && id[j] < bx);
        bv = take ? a[j] : bv; bx = take ? id[j] : bx; bslot = take ? j : bslot;
      }
      int bl = l;
      #pragma unroll
      for (int sft = 1; sft < 64; sft <<= 1) {
        float ov = __shfl_xor(bv, sft, 64);
        int  oxx = __shfl_xor(bx, sft, 64);
        int  ol  = __shfl_xor(bl, sft, 64);
        bool take = (ov > bv) || (ov == bv && oxx < bx);
        if (take) { bv = ov; bx = oxx; bl = ol; }
      }
      if (l == 0) fl[it] = bx;
      if (l == bl) {
        #pragma unroll
        for (int j = 0; j < 6; ++j) if (j == bslot) a[j] = -INFINITY;
      }
    }
  }
  __syncthreads();

  // gather knn (bf16): 4 rows per pass, 128 lanes x float4 per row
  #pragma unroll 4
  for (int rr = 0; rr < 32; rr += 4) {
    int r = rr + (t >> 7);
    int row = fl[r];
    int d4 = t & 127;
    float4 v = *(const float4*)(keys + (size_t)row*DD + d4*4);
    ushort4 h; h.x = f2bf_n(v.x); h.y = f2bf_n(v.y); h.z = f2bf_n(v.z); h.w = f2bf_n(v.w);
    *(ushort4*)&knnb[r*520 + d4*4] = h;
  }
  __syncthreads();

  // MFMA knn@Wm: 8 waves, each wave 2 A-col tiles (a = (w*2+n)*16 + c)
  f32x4 acc[2][2];
  #pragma unroll
  for (int m = 0; m < 2; ++m)
    #pragma unroll
    for (int n = 0; n < 2; ++n) acc[m][n] = (f32x4){0.f,0.f,0.f,0.f};
  const short8_t* wmf8 = (const short8_t*)wmf;
  for (int ks = 0; ks < 16; ++ks) {
    short8_t af[2], bf[2];
    #pragma unroll
    for (int m = 0; m < 2; ++m) af[m] = *(const short8_t*)&knnb[(m*16 + c)*520 + ks*32 + g*8];
    #pragma unroll
    for (int n = 0; n < 2; ++n) bf[n] = wmf8[((w*2 + n)*64 + ks*4 + g)*16 + c];
    #pragma unroll
    for (int m = 0; m < 2; ++m)
      #pragma unroll
      for (int n = 0; n < 2; ++n) acc[m][n] = mfma_bf16(af[m], bf[n], acc[m][n]);
  }

  float p[8] = {0.f,0.f,0.f,0.f,0.f,0.f,0.f,0.f};
  #pragma unroll
  for (int n = 0; n < 2; ++n) {
    int a = w*32 + n*16 + c;
    float qv = qqb[a], wv = wsl[a];
    #pragma unroll
    for (int m = 0; m < 2; ++m)
      #pragma unroll
      for (int r = 0; r < 4; ++r)
        p[m*4 + r] += fast_tanh(acc[m][n][r] + qv) * wv;
  }
  #pragma unroll
  for (int sft = 1; sft < 16; sft <<= 1)
    #pragma unroll
    for (int i = 0; i < 8; ++i) p[i] += __shfl_xor(p[i], sft, 64);
  if (c == 0) {
    #pragma unroll
    for (int m = 0; m < 2; ++m)
      #pragma unroll
      for (int r = 0; r < 4; ++r) spart[w][m*16 + g*4 + r] = p[m*4 + r];
  }
  __syncthreads();

  if (t < 32) {
    float s = bsc[0];
    #pragma unroll
    for (int ww = 0; ww < 8; ++ww) s += spart[ww][t];
    float mx = s;
    #pragma unroll
    for (int sft = 1; sft < 32; sft <<= 1) mx = fmaxf(mx, __shfl_xor(mx, sft, 64));
    float e = __expf(s - mx);
    float su = e;
    #pragma unroll
    for (int sft = 1; sft < 32; sft <<= 1) su += __shfl_xor(su, sft, 64);
    wexp[t] = e / su;
  }
  __syncthreads();

  {
    int d = t;   // 512 threads cover all 512 dims in one pass
    float s = 0.f;
    #pragma unroll
    for (int k = 0; k < 32; ++k) s += wexp[k] * bf2f(knnb[k*520 + d]);
    attf[(((q>>4)*64 + (d>>3))*16 + (q&15))*8 + (d&7)] = f2bf(s);
  }
}

// ---------------- K3b: out = [q, attended] @ Wc + bc  (28 blocks: 7 col-tiles x 4 row-groups) ----------------
__global__ __launch_bounds__(256) void k3b_cls(const float* __restrict__ Wc,
                                               const unsigned short* __restrict__ qf,
                                               const unsigned short* __restrict__ attf,
                                               const float* __restrict__ bc,
                                               float* __restrict__ out) {
  __shared__ unsigned short wb[128*16*8];   // 32 KB
  int bn = blockIdx.x % 7, rg = blockIdx.x / 7;
  int t = threadIdx.x;
  int w = t >> 6, l = t & 63, g = l >> 4, c = l & 15;
  #pragma unroll
  for (int i = 0; i < 64; ++i) {
    int d = i*16 + (t>>4); int a = t & 15;
    int col = bn*16 + a;
    float vv = (col < CD) ? Wc[d*CD + col] : 0.f;
    wb[((d>>3)*16 + a)*8 + (d&7)] = f2bf(vv);
  }
  __syncthreads();
  const short8_t* qf8 = (const short8_t*)qf;
  const short8_t* af8 = (const short8_t*)attf;
  const short8_t* wb8 = (const short8_t*)wb;
  int M = rg*4 + w;                         // this wave's 16-row tile (0..15)
  f32x4 acc = (f32x4){0.f,0.f,0.f,0.f};
  for (int kt = 0; kt < 32; ++kt) {
    short8_t bfr = wb8[(kt*4 + g)*16 + c];
    const short8_t* asrc = (kt < 16) ? qf8 : af8;
    int kbase = (kt & 15)*4 + g;
    short8_t afr = asrc[(M*64 + kbase)*16 + c];
    acc = mfma_bf16(afr, bfr, acc);
  }
  int col = bn*16 + c;
  if (col < CD) {
    float bias = bc[col];
    #pragma unroll
    for (int r = 0; r < 4; ++r)
      out[(M*16 + g*4 + r)*CD + col] = acc[r] + bias;
  }
}

// ---------------- launch ----------------
extern "C" void kernel_launch(void* const* d_in, const int* in_sizes, int n_in,
                              void* d_out, int out_size, void* d_ws, size_t ws_size,
                              hipStream_t stream) {
  const float* qfeat = (const float*)d_in[0];
  const float* keys  = (const float*)d_in[1];
  const float* Wq    = (const float*)d_in[2];
  const float* bq    = (const float*)d_in[3];
  const float* Wm    = (const float*)d_in[4];
  const float* bm    = (const float*)d_in[5];
  const float* Ws    = (const float*)d_in[6];
  const float* bsc   = (const float*)d_in[7];
  const float* Wc    = (const float*)d_in[8];
  const float* bc    = (const float*)d_in[9];
  float* out = (float*)d_out;

  char* ws = (char*)d_ws;
  unsigned short* qf   = (unsigned short*)(ws + 0);          // 262144 B
  float*          qr   = (float*)(ws + 262144);              // 524288 B
  float*          qn   = (float*)(ws + 786432);              // 1024 B
  unsigned short* wmf  = (unsigned short*)(ws + 787456);     // 262144 B
  float*          qq   = (float*)(ws + 1049600);             // 262144 B
  unsigned short* attf = (unsigned short*)(ws + 1311744);    // 262144 B
  float*          wtopv= (float*)(ws + 1573888);             // 393216 B
  int*            wtopi= (int*)(ws + 1967104);               // 393216 B
  unsigned int*   cand = (unsigned int*)(ws + 2360320);      // 19203072 B

  k0_prep   <<<768,      256, 0, stream>>>(qfeat, Wm, qr, qf, qn, wmf);
  k1_fused  <<<NB + 64,  256, 0, stream>>>(keys, qf, cand, Wq, bq, bm, qq);
  k2a_reduce<<<BQ*NPART, 256, 0, stream>>>(cand, qr, qn, keys, wtopv, wtopi);
  k23ab     <<<BQ,       512, 0, stream>>>(wtopv, wtopi, keys, qq, wmf, Ws, bsc, attf);
  k3b_cls   <<<28,       256, 0, stream>>>(Wc, qf, attf, bc, out);
}

// Round 22
// 167.263 us; speedup vs baseline: 1.0250x; 1.0005x over previous
//
#include <hip/hip_runtime.h>
#include <hip/hip_bf16.h>
#include <hip/hip_fp16.h>

// Problem constants
#define BQ    256
#define NKEY  100000
#define DD    512
#define AD    256
#define CD    100
#define KSEL  32
#define KB    64            // keys per K1 block
#define NB    1563          // ceil(NKEY/KB)
#define CPQ   (NB*12)       // cand entries per query = 18756

// selection params (round-17-validated)
#define NPART 8             // k2a blocks per query
#define WTOP  12            // per-wave top list emitted by k2a
#define NC2   (NPART*4*WTOP)  // 384 rescore candidates per query
#define TLA   6             // per-lane list depth in k2a

typedef __attribute__((ext_vector_type(8))) short  short8_t;
typedef __attribute__((ext_vector_type(8))) __bf16 bf16x8;
typedef __attribute__((ext_vector_type(4))) float  f32x4;

__device__ __forceinline__ unsigned short f2bf(float x) {
  unsigned int u = __float_as_uint(x);
  return (unsigned short)((u + 0x7FFFu + ((u >> 16) & 1u)) >> 16);  // RTNE
}
__device__ __forceinline__ unsigned short f2bf_n(float x) {
  __bf16 h = (__bf16)x;                 // native cvt, pairs into v_cvt_pk_bf16_f32
  return __builtin_bit_cast(unsigned short, h);
}
__device__ __forceinline__ float bf2f(unsigned short h) {
  return __uint_as_float(((unsigned int)h) << 16);
}
__device__ __forceinline__ f32x4 mfma_bf16(short8_t a, short8_t b, f32x4 c) {
  return __builtin_amdgcn_mfma_f32_16x16x32_bf16(
      __builtin_bit_cast(bf16x8, a), __builtin_bit_cast(bf16x8, b), c, 0, 0, 0);
}
__device__ __forceinline__ float fast_tanh(float x) {
  x = fminf(fmaxf(x, -15.f), 15.f);
  float e = __expf(2.f * x);
  return (e - 1.f) * __builtin_amdgcn_rcpf(e + 1.f);
}

template<int T>
__device__ __forceinline__ void topk_insert(float (&v)[T], int (&ix)[T], float val, int idx) {
  if (val <= v[T-1]) return;
  v[T-1] = val; ix[T-1] = idx;
  #pragma unroll
  for (int j = T-1; j > 0; --j) {
    bool sw = v[j] > v[j-1];
    float tv = sw ? v[j] : v[j-1];  float uv = sw ? v[j-1] : v[j];
    int   ti = sw ? ix[j] : ix[j-1]; int  ui = sw ? ix[j-1] : ix[j];
    v[j-1] = tv; v[j] = uv; ix[j-1] = ti; ix[j] = ui;
  }
}

// ---------------- K0: query prep only (256 blocks; Wm moved into k1_fused tail) ----------------
__global__ __launch_bounds__(256) void k0_prep(const float* __restrict__ qfeat,
                                               float* __restrict__ qr,
                                               unsigned short* __restrict__ qf,
                                               float* __restrict__ qn) {
  int b = blockIdx.x, t = threadIdx.x;
  float s = 0.f;
  #pragma unroll
  for (int p = 0; p < 2; ++p) {
    int k = t + p*256;
    float v = qfeat[b*DD + k];
    v = v > 0.f ? v : 0.f;
    qr[b*DD + k] = v;
    qf[(((b>>4)*64 + (k>>3))*16 + (b&15))*8 + (k&7)] = f2bf(v);
    s += v*v;
  }
  __shared__ float red[4];
  #pragma unroll
  for (int st = 1; st < 64; st <<= 1) s += __shfl_xor(s, st, 64);
  if ((t & 63) == 0) red[t>>6] = s;
  __syncthreads();
  if (t == 0) qn[b] = sqrtf(red[0]+red[1]+red[2]+red[3]);
}

// ---------------- K1 (fused): 0..NB-1 coarse GEMM; NB..NB+63 qq GEMM; NB+64..NB+575 Wm frag ----------------
__global__ __launch_bounds__(256) void k1_fused(const float* __restrict__ keys,
                                                const unsigned short* __restrict__ qf,
                                                unsigned int* __restrict__ cand,
                                                const float* __restrict__ Wq,
                                                const float* __restrict__ bq,
                                                const float* __restrict__ bm,
                                                float* __restrict__ qq,
                                                const float* __restrict__ Wm,
                                                unsigned short* __restrict__ wmf) {
  __shared__ __align__(16) char shmem[16640];   // aliased: k1 uses 8.4KB, qq path 16KB
  int b = blockIdx.x, t = threadIdx.x;
  int w = t >> 6, l = t & 63, g = l >> 4, c = l & 15;
  const short8_t* qf8 = (const short8_t*)qf;

  if (b >= NB) {
    int bb = b - NB;
    if (bb >= 64) {
      // ---- Wm fragmenting path (512 blocks; consumed by k23ab, rides k1's tail) ----
      int i = (bb - 64)*256 + t;   // i = d*256 + a, 131072 total
      int d = i >> 8, a = i & 255;
      wmf[(((a>>4)*64 + (d>>3))*16 + (a&15))*8 + (d&7)] = f2bf(Wm[i]);
      return;
    }
    // ---- k_qq path ----
    unsigned short* wb = (unsigned short*)shmem;   // 16 KB
    int bn = bb & 15, rg = bb >> 4;
    #pragma unroll
    for (int i = 0; i < 32; ++i) {
      int d = i*16 + (t>>4); int a = t & 15;
      wb[((d>>3)*16 + a)*8 + (d&7)] = f2bf(Wq[d*AD + bn*16 + a]);
    }
    __syncthreads();
    const short8_t* wb8 = (const short8_t*)wb;
    f32x4 acc = (f32x4){0.f,0.f,0.f,0.f};
    int M = rg*4 + w;
    for (int kt = 0; kt < 16; ++kt) {
      short8_t bfr = wb8[(kt*4 + g)*16 + c];
      short8_t afr = qf8[(M*64 + kt*4 + g)*16 + c];
      acc = mfma_bf16(afr, bfr, acc);
    }
    int col = bn*16 + c;
    float bias = bq[col] + bm[col];
    #pragma unroll
    for (int r = 0; r < 4; ++r)
      qq[(M*16 + g*4 + r)*AD + col] = acc[r] + bias;
    return;
  }

  // ---- k1 path ----
  short8_t* Abf8 = (short8_t*)shmem;             // 8 KB
  float* invkn = (float*)(shmem + 8192);         // 256 B
  int kb0 = b*KB;

  f32x4 acc[4][4];   // [key m-tile][query n-tile]
  #pragma unroll
  for (int m = 0; m < 4; ++m)
    #pragma unroll
    for (int n = 0; n < 4; ++n) acc[m][n] = (f32x4){0.f,0.f,0.f,0.f};

  // staging assignment: thread t stages rows r1,r2 dim-granule gb
  int r1 = t >> 3, gb = t & 7;
  int r2 = 32 + r1;
  int swz = gb ^ (r1 & 7);                 // r2&7 == r1&7
  int row1 = kb0 + r1; row1 = row1 < NKEY ? row1 : NKEY-1;
  int row2 = kb0 + r2; row2 = row2 < NKEY ? row2 : NKEY-1;
  const float* src1 = keys + (size_t)row1*DD + gb*8;
  const float* src2 = keys + (size_t)row2*DD + gb*8;
  float ksq1 = 0.f, ksq2 = 0.f;

  // prologue: B(0) [8 instr], then G(0) -> Ge [4], G(1) -> Go [4]
  short8_t Bcur[2][4];
  #pragma unroll
  for (int kt = 0; kt < 2; ++kt)
    #pragma unroll
    for (int n = 0; n < 4; ++n)
      Bcur[kt][n] = qf8[((w*4 + n)*64 + kt*4 + g)*16 + c];
  __builtin_amdgcn_sched_barrier(0);
  float4 Ge[4], Go[4];
  Ge[0] = *(const float4*)(src1);      Ge[1] = *(const float4*)(src1 + 4);
  Ge[2] = *(const float4*)(src2);      Ge[3] = *(const float4*)(src2 + 4);
  __builtin_amdgcn_sched_barrier(0);
  Go[0] = *(const float4*)(src1 + 64); Go[1] = *(const float4*)(src1 + 68);
  Go[2] = *(const float4*)(src2 + 64); Go[3] = *(const float4*)(src2 + 68);

  auto body = [&](int ks8, float4 (&Gc)[4]) {
    if (ks8 < 7) asm volatile("s_waitcnt vmcnt(4)" ::: "memory");
    else         asm volatile("s_waitcnt vmcnt(0)" ::: "memory");
    // norms + cvt from registers
    ksq1 += Gc[0].x*Gc[0].x + Gc[0].y*Gc[0].y + Gc[0].z*Gc[0].z + Gc[0].w*Gc[0].w
          + Gc[1].x*Gc[1].x + Gc[1].y*Gc[1].y + Gc[1].z*Gc[1].z + Gc[1].w*Gc[1].w;
    ksq2 += Gc[2].x*Gc[2].x + Gc[2].y*Gc[2].y + Gc[2].z*Gc[2].z + Gc[2].w*Gc[2].w
          + Gc[3].x*Gc[3].x + Gc[3].y*Gc[3].y + Gc[3].z*Gc[3].z + Gc[3].w*Gc[3].w;
    short8_t w1, w2;
    w1[0] = (short)f2bf_n(Gc[0].x); w1[1] = (short)f2bf_n(Gc[0].y);
    w1[2] = (short)f2bf_n(Gc[0].z); w1[3] = (short)f2bf_n(Gc[0].w);
    w1[4] = (short)f2bf_n(Gc[1].x); w1[5] = (short)f2bf_n(Gc[1].y);
    w1[6] = (short)f2bf_n(Gc[1].z); w1[7] = (short)f2bf_n(Gc[1].w);
    w2[0] = (short)f2bf_n(Gc[2].x); w2[1] = (short)f2bf_n(Gc[2].y);
    w2[2] = (short)f2bf_n(Gc[2].z); w2[3] = (short)f2bf_n(Gc[2].w);
    w2[4] = (short)f2bf_n(Gc[3].x); w2[5] = (short)f2bf_n(Gc[3].y);
    w2[6] = (short)f2bf_n(Gc[3].z); w2[7] = (short)f2bf_n(Gc[3].w);
    __builtin_amdgcn_s_barrier();                       // prev-iter LDS reads done
    Abf8[r1*8 + swz] = w1;
    Abf8[r2*8 + swz] = w2;
    short8_t Bnxt[2][4];
    if (ks8 < 7) {
      #pragma unroll
      for (int kt = 0; kt < 2; ++kt)
        #pragma unroll
        for (int n = 0; n < 4; ++n)
          Bnxt[kt][n] = qf8[((w*4 + n)*64 + (ks8+1)*8 + kt*4 + g)*16 + c];
    }
    __builtin_amdgcn_sched_barrier(0);                  // pin B(t+1) before G(t+2)
    if (ks8 < 6) {
      Gc[0] = *(const float4*)(src1 + (ks8+2)*64);
      Gc[1] = *(const float4*)(src1 + (ks8+2)*64 + 4);
      Gc[2] = *(const float4*)(src2 + (ks8+2)*64);
      Gc[3] = *(const float4*)(src2 + (ks8+2)*64 + 4);
    }
    asm volatile("s_waitcnt lgkmcnt(0)" ::: "memory");  // own ds_writes visible
    __builtin_amdgcn_s_barrier();
    __builtin_amdgcn_sched_barrier(0);
    int p = c & 7;
    #pragma unroll
    for (int kt = 0; kt < 2; ++kt) {
      #pragma unroll
      for (int m = 0; m < 4; ++m) {
        short8_t A = Abf8[(m*16 + c)*8 + ((kt*4 + g) ^ p)];
        #pragma unroll
        for (int n = 0; n < 4; ++n) acc[m][n] = mfma_bf16(A, Bcur[kt][n], acc[m][n]);
      }
    }
    if (ks8 < 7) {
      #pragma unroll
      for (int kt = 0; kt < 2; ++kt)
        #pragma unroll
        for (int n = 0; n < 4; ++n) Bcur[kt][n] = Bnxt[kt][n];
    }
  };

  #pragma unroll
  for (int ks8 = 0; ks8 < 8; ++ks8) {
    if (ks8 & 1) body(ks8, Go);
    else         body(ks8, Ge);
  }

  // norms: reduce over the 8 gb-threads of each row (lanes differ in bits 0..2)
  ksq1 += __shfl_xor(ksq1, 1, 64); ksq1 += __shfl_xor(ksq1, 2, 64); ksq1 += __shfl_xor(ksq1, 4, 64);
  ksq2 += __shfl_xor(ksq2, 1, 64); ksq2 += __shfl_xor(ksq2, 2, 64); ksq2 += __shfl_xor(ksq2, 4, 64);
  if ((t & 7) == 0) {
    invkn[r1] = ksq1 > 0.f ? rsqrtf(ksq1) : 0.f;
    invkn[r2] = ksq2 > 0.f ? rsqrtf(ksq2) : 0.f;
  }
  __syncthreads();

  float ikv[16];
  #pragma unroll
  for (int m = 0; m < 4; ++m)
    #pragma unroll
    for (int r = 0; r < 4; ++r) ikv[m*4 + r] = invkn[m*16 + g*4 + r];

  // per-lane branchless top-3 of the lane's 16 keys, per query column
  #pragma unroll
  for (int n = 0; n < 4; ++n) {
    float v1 = -3.0e38f, v2 = -3.0e38f, v3 = -3.0e38f;
    int   i1 = 0, i2 = 0, i3 = 0;
    #pragma unroll
    for (int m = 0; m < 4; ++m)
      #pragma unroll
      for (int r = 0; r < 4; ++r) {
        int lid = m*16 + g*4 + r;
        bool valid = (kb0 + lid) < NKEY;
        float v = valid ? acc[m][n][r] * ikv[m*4 + r] : -3.0e38f;
        bool gt1 = v > v1, gt2 = v > v2, gt3 = v > v3;
        v3 = gt2 ? v2 : (gt3 ? v : v3);  i3 = gt2 ? i2 : (gt3 ? lid : i3);
        v2 = gt1 ? v1 : (gt2 ? v : v2);  i2 = gt1 ? i1 : (gt2 ? lid : i2);
        v1 = gt1 ? v  : v1;              i1 = gt1 ? lid : i1;
      }
    int q = w*64 + n*16 + c;
    unsigned int base = ((unsigned int)q*NB + (unsigned int)b)*12u + (unsigned int)g*3u;
    cand[base + 0] = ((unsigned int)__half_as_ushort(__float2half(v1)) << 16) | (unsigned int)i1;
    cand[base + 1] = ((unsigned int)__half_as_ushort(__float2half(v2)) << 16) | (unsigned int)i2;
    cand[base + 2] = ((unsigned int)__half_as_ushort(__float2half(v3)) << 16) | (unsigned int)i3;
  }
}

// ---------------- K2a: candidate reduce + EXACT fp32 rescore (8 blocks/query, 32 waves/CU) ----------------
__global__ __launch_bounds__(256) void k2a_reduce(const unsigned int* __restrict__ cand,
                                                  const float* __restrict__ qr,
                                                  const float* __restrict__ qn,
                                                  const float* __restrict__ keys,
                                                  float* __restrict__ wtopv,
                                                  int* __restrict__ wtopi) {
  int bid = blockIdx.x;
  int q = bid >> 3, p = bid & 7;
  int t = threadIdx.x, w = t >> 6, l = t & 63;
  const unsigned int* cq = cand + (size_t)q * CPQ;

  const int PER_PART = (CPQ + NPART - 1) / NPART;   // 2345
  const int PER_WAVE = (PER_PART + 3) / 4;          // 587
  int pbase = p * PER_PART;
  int start = pbase + w * PER_WAVE;
  int end   = pbase + PER_PART;
  if (start + PER_WAVE < end) end = start + PER_WAVE;
  if (end > CPQ) end = CPQ;

  float v[TLA]; int ix[TLA];
  #pragma unroll
  for (int j = 0; j < TLA; ++j) { v[j] = -INFINITY; ix[j] = -1; }
  for (int i = start + l; i < end; i += 64) {
    unsigned int pk = cq[i];
    float val = __half2float(__ushort_as_half((unsigned short)(pk >> 16)));
    int bb = i / 12;                       // compiler magic-mul
    int idx = (bb << 6) | (int)(pk & 63u);
    topk_insert<TLA>(v, ix, val, idx);
  }

  // wave merge: exact wave top-WTOP; winning index is wave-uniform -> keep in regs
  int idxs[WTOP];
  for (int it = 0; it < WTOP; ++it) {
    float bv = v[0]; int bx = ix[0]; int bl = l;
    #pragma unroll
    for (int sft = 1; sft < 64; sft <<= 1) {
      float ov = __shfl_xor(bv, sft, 64);
      int  oxx = __shfl_xor(bx, sft, 64);
      int  ol  = __shfl_xor(bl, sft, 64);
      bool take = (ov > bv) || (ov == bv && ol < bl);
      if (take) { bv = ov; bx = oxx; bl = ol; }
    }
    idxs[it] = bx;
    if (l == bl) {
      #pragma unroll
      for (int j = 0; j < TLA-1; ++j) { v[j] = v[j+1]; ix[j] = ix[j+1]; }
      v[TLA-1] = -INFINITY; ix[TLA-1] = -1;
    }
  }

  // exact fp32 rescore of this wave's 12 candidates (2-deep row pipeline; lane = 8-dim slice)
  const float4* q4 = (const float4*)(qr + (size_t)q*DD + l*8);
  float4 qa0 = q4[0], qa1 = q4[1];
  float qnv = qn[q];
  int obase = (q * NPART + p) * 4 * WTOP + w * WTOP;

  int nidx = idxs[0];
  const float4* kr = (const float4*)(keys + (size_t)((nidx < 0 || nidx >= NKEY) ? 0 : nidx)*DD + l*8);
  float4 k0v = kr[0], k1v = kr[1];
  for (int j = 0; j < WTOP; ++j) {
    int curidx = idxs[j];
    bool bad = (curidx < 0) || (curidx >= NKEY);
    float4 c0 = k0v, c1 = k1v;
    if (j + 1 < WTOP) {
      nidx = idxs[j+1];
      kr = (const float4*)(keys + (size_t)((nidx < 0 || nidx >= NKEY) ? 0 : nidx)*DD + l*8);
      k0v = kr[0]; k1v = kr[1];
    }
    float dot = qa0.x*c0.x + qa0.y*c0.y + qa0.z*c0.z + qa0.w*c0.w
              + qa1.x*c1.x + qa1.y*c1.y + qa1.z*c1.z + qa1.w*c1.w;
    float ks  = c0.x*c0.x + c0.y*c0.y + c0.z*c0.z + c0.w*c0.w
              + c1.x*c1.x + c1.y*c1.y + c1.z*c1.z + c1.w*c1.w;
    #pragma unroll
    for (int sft = 1; sft < 64; sft <<= 1) {
      dot += __shfl_xor(dot, sft, 64);
      ks  += __shfl_xor(ks,  sft, 64);
    }
    if (l == 0) {
      float den = fmaxf(qnv * sqrtf(ks), 1e-8f);
      wtopv[obase + j] = bad ? -1e30f : dot/den;
      wtopi[obase + j] = bad ? 0 : curidx;
    }
  }
}

// ---------------- K23ab (512 threads): top-32 select -> gather -> attention -> attf ----------------
__global__ __launch_bounds__(512) void k23ab(const float* __restrict__ wtopv,
                                             const int* __restrict__ wtopi,
                                             const float* __restrict__ keys,
                                             const float* __restrict__ qq,
                                             const unsigned short* __restrict__ wmf,
                                             const float* __restrict__ Ws,
                                             const float* __restrict__ bsc,
                                             unsigned short* __restrict__ attf) {
  int q = blockIdx.x, t = threadIdx.x, w = t >> 6, l = t & 63, g = l >> 4, c = l & 15;
  __shared__ float simx[NC2];
  __shared__ int   sidx[NC2];
  __shared__ int   fl[KSEL];
  __shared__ float qqb[256];
  __shared__ float wsl[256];
  __shared__ unsigned short knnb[32*520];
  __shared__ float spart[8][32];
  __shared__ float wexp[32];

  if (t < 256) {
    qqb[t] = qq[q*AD + t];
    wsl[t] = Ws[t];
  }
  for (int i = t; i < NC2; i += 512) {
    simx[i] = wtopv[q*NC2 + i];
    int idx = wtopi[q*NC2 + i];
    sidx[i] = (idx < 0 || idx >= NKEY) ? 0 : idx;
  }
  __syncthreads();

  // wave 0: exact top-32 of 384, tie-break value desc then index asc (lax.top_k)
  if (w == 0) {
    float a[6]; int id[6];
    #pragma unroll
    for (int j = 0; j < 6; ++j) { a[j] = simx[j*64 + l]; id[j] = sidx[j*64 + l]; }
    for (int it = 0; it < KSEL; ++it) {
      float bv = a[0]; int bx = id[0]; int bslot = 0;
      #pragma unroll
      for (int j = 1; j < 6; ++j) {
        bool take = (a[j] > bv) || (a[j] == bv && id[j] < bx);
        bv = take ? a[j] : bv; bx = take ? id[j] : bx; bslot = take ? j : bslot;
      }
      int bl = l;
      #pragma unroll
      for (int sft = 1; sft < 64; sft <<= 1) {
        float ov = __shfl_xor(bv, sft, 64);
        int  oxx = __shfl_xor(bx, sft, 64);
        int  ol  = __shfl_xor(bl, sft, 64);
        bool take = (ov > bv) || (ov == bv && oxx < bx);
        if (take) { bv = ov; bx = oxx; bl = ol; }
      }
      if (l == 0) fl[it] = bx;
      if (l == bl) {
        #pragma unroll
        for (int j = 0; j < 6; ++j) if (j == bslot) a[j] = -INFINITY;
      }
    }
  }
  __syncthreads();

  // gather knn (bf16): 4 rows per pass, 128 lanes x float4 per row
  #pragma unroll 4
  for (int rr = 0; rr < 32; rr += 4) {
    int r = rr + (t >> 7);
    int row = fl[r];
    int d4 = t & 127;
    float4 v = *(const float4*)(keys + (size_t)row*DD + d4*4);
    ushort4 h; h.x = f2bf_n(v.x); h.y = f2bf_n(v.y); h.z = f2bf_n(v.z); h.w = f2bf_n(v.w);
    *(ushort4*)&knnb[r*520 + d4*4] = h;
  }
  __syncthreads();

  // MFMA knn@Wm: 8 waves, each wave 2 A-col tiles (a = (w*2+n)*16 + c)
  f32x4 acc[2][2];
  #pragma unroll
  for (int m = 0; m < 2; ++m)
    #pragma unroll
    for (int n = 0; n < 2; ++n) acc[m][n] = (f32x4){0.f,0.f,0.f,0.f};
  const short8_t* wmf8 = (const short8_t*)wmf;
  for (int ks = 0; ks < 16; ++ks) {
    short8_t af[2], bf[2];
    #pragma unroll
    for (int m = 0; m < 2; ++m) af[m] = *(const short8_t*)&knnb[(m*16 + c)*520 + ks*32 + g*8];
    #pragma unroll
    for (int n = 0; n < 2; ++n) bf[n] = wmf8[((w*2 + n)*64 + ks*4 + g)*16 + c];
    #pragma unroll
    for (int m = 0; m < 2; ++m)
      #pragma unroll
      for (int n = 0; n < 2; ++n) acc[m][n] = mfma_bf16(af[m], bf[n], acc[m][n]);
  }

  float p[8] = {0.f,0.f,0.f,0.f,0.f,0.f,0.f,0.f};
  #pragma unroll
  for (int n = 0; n < 2; ++n) {
    int a = w*32 + n*16 + c;
    float qv = qqb[a], wv = wsl[a];
    #pragma unroll
    for (int m = 0; m < 2; ++m)
      #pragma unroll
      for (int r = 0; r < 4; ++r)
        p[m*4 + r] += fast_tanh(acc[m][n][r] + qv) * wv;
  }
  #pragma unroll
  for (int sft = 1; sft < 16; sft <<= 1)
    #pragma unroll
    for (int i = 0; i < 8; ++i) p[i] += __shfl_xor(p[i], sft, 64);
  if (c == 0) {
    #pragma unroll
    for (int m = 0; m < 2; ++m)
      #pragma unroll
      for (int r = 0; r < 4; ++r) spart[w][m*16 + g*4 + r] = p[m*4 + r];
  }
  __syncthreads();

  if (t < 32) {
    float s = bsc[0];
    #pragma unroll
    for (int ww = 0; ww < 8; ++ww) s += spart[ww][t];
    float mx = s;
    #pragma unroll
    for (int sft = 1; sft < 32; sft <<= 1) mx = fmaxf(mx, __shfl_xor(mx, sft, 64));
    float e = __expf(s - mx);
    float su = e;
    #pragma unroll
    for (int sft = 1; sft < 32; sft <<= 1) su += __shfl_xor(su, sft, 64);
    wexp[t] = e / su;
  }
  __syncthreads();

  {
    int d = t;   // 512 threads cover all 512 dims in one pass
    float s = 0.f;
    #pragma unroll
    for (int k = 0; k < 32; ++k) s += wexp[k] * bf2f(knnb[k*520 + d]);
    attf[(((q>>4)*64 + (d>>3))*16 + (q&15))*8 + (d&7)] = f2bf(s);
  }
}

// ---------------- K3b: out = [q, attended] @ Wc + bc  (28 blocks: 7 col-tiles x 4 row-groups) ----------------
__global__ __launch_bounds__(256) void k3b_cls(const float* __restrict__ Wc,
                                               const unsigned short* __restrict__ qf,
                                               const unsigned short* __restrict__ attf,
                                               const float* __restrict__ bc,
                                               float* __restrict__ out) {
  __shared__ unsigned short wb[128*16*8];   // 32 KB
  int bn = blockIdx.x % 7, rg = blockIdx.x / 7;
  int t = threadIdx.x;
  int w = t >> 6, l = t & 63, g = l >> 4, c = l & 15;
  #pragma unroll
  for (int i = 0; i < 64; ++i) {
    int d = i*16 + (t>>4); int a = t & 15;
    int col = bn*16 + a;
    float vv = (col < CD) ? Wc[d*CD + col] : 0.f;
    wb[((d>>3)*16 + a)*8 + (d&7)] = f2bf(vv);
  }
  __syncthreads();
  const short8_t* qf8 = (const short8_t*)qf;
  const short8_t* af8 = (const short8_t*)attf;
  const short8_t* wb8 = (const short8_t*)wb;
  int M = rg*4 + w;                         // this wave's 16-row tile (0..15)
  f32x4 acc = (f32x4){0.f,0.f,0.f,0.f};
  for (int kt = 0; kt < 32; ++kt) {
    short8_t bfr = wb8[(kt*4 + g)*16 + c];
    const short8_t* asrc = (kt < 16) ? qf8 : af8;
    int kbase = (kt & 15)*4 + g;
    short8_t afr = asrc[(M*64 + kbase)*16 + c];
    acc = mfma_bf16(afr, bfr, acc);
  }
  int col = bn*16 + c;
  if (col < CD) {
    float bias = bc[col];
    #pragma unroll
    for (int r = 0; r < 4; ++r)
      out[(M*16 + g*4 + r)*CD + col] = acc[r] + bias;
  }
}

// ---------------- launch ----------------
extern "C" void kernel_launch(void* const* d_in, const int* in_sizes, int n_in,
                              void* d_out, int out_size, void* d_ws, size_t ws_size,
                              hipStream_t stream) {
  const float* qfeat = (const float*)d_in[0];
  const float* keys  = (const float*)d_in[1];
  const float* Wq    = (const float*)d_in[2];
  const float* bq    = (const float*)d_in[3];
  const float* Wm    = (const float*)d_in[4];
  const float* bm    = (const float*)d_in[5];
  const float* Ws    = (const float*)d_in[6];
  const float* bsc   = (const float*)d_in[7];
  const float* Wc    = (const float*)d_in[8];
  const float* bc    = (const float*)d_in[9];
  float* out = (float*)d_out;

  char* ws = (char*)d_ws;
  unsigned short* qf   = (unsigned short*)(ws + 0);          // 262144 B
  float*          qr   = (float*)(ws + 262144);              // 524288 B
  float*          qn   = (float*)(ws + 786432);              // 1024 B
  unsigned short* wmf  = (unsigned short*)(ws + 787456);     // 262144 B
  float*          qq   = (float*)(ws + 1049600);             // 262144 B
  unsigned short* attf = (unsigned short*)(ws + 1311744);    // 262144 B
  float*          wtopv= (float*)(ws + 1573888);             // 393216 B
  int*            wtopi= (int*)(ws + 1967104);               // 393216 B
  unsigned int*   cand = (unsigned int*)(ws + 2360320);      // 19203072 B

  k0_prep   <<<BQ,       256, 0, stream>>>(qfeat, qr, qf, qn);
  k1_fused  <<<NB + 576, 256, 0, stream>>>(keys, qf, cand, Wq, bq, bm, qq, Wm, wmf);
  k2a_reduce<<<BQ*NPART, 256, 0, stream>>>(cand, qr, qn, keys, wtopv, wtopi);
  k23ab     <<<BQ,       512, 0, stream>>>(wtopv, wtopi, keys, qq, wmf, Ws, bsc, attf);
  k3b_cls   <<<28,       256, 0, stream>>>(Wc, qf, attf, bc, out);
}

// Round 23
// 165.250 us; speedup vs baseline: 1.0375x; 1.0122x over previous
//
#include <hip/hip_runtime.h>
#include <hip/hip_bf16.h>
#include <hip/hip_fp16.h>

// Problem constants
#define BQ    256
#define NKEY  100000
#define DD    512
#define AD    256
#define CD    100
#define KSEL  32
#define KB    64            // keys per K1 block
#define NB    1563          // ceil(NKEY/KB)
#define CPQ   (NB*12)       // cand entries per query = 18756

// selection params (round-17-validated)
#define NPART 8             // k2a blocks per query
#define WTOP  12            // per-wave top list emitted by k2a
#define NC2   (NPART*4*WTOP)  // 384 rescore candidates per query
#define TLA   6             // per-lane list depth in k2a

typedef __attribute__((ext_vector_type(8))) short  short8_t;
typedef __attribute__((ext_vector_type(8))) __bf16 bf16x8;
typedef __attribute__((ext_vector_type(4))) float  f32x4;

__device__ __forceinline__ unsigned short f2bf(float x) {
  unsigned int u = __float_as_uint(x);
  return (unsigned short)((u + 0x7FFFu + ((u >> 16) & 1u)) >> 16);  // RTNE
}
__device__ __forceinline__ unsigned short f2bf_n(float x) {
  __bf16 h = (__bf16)x;                 // native cvt, pairs into v_cvt_pk_bf16_f32
  return __builtin_bit_cast(unsigned short, h);
}
__device__ __forceinline__ float bf2f(unsigned short h) {
  return __uint_as_float(((unsigned int)h) << 16);
}
__device__ __forceinline__ f32x4 mfma_bf16(short8_t a, short8_t b, f32x4 c) {
  return __builtin_amdgcn_mfma_f32_16x16x32_bf16(
      __builtin_bit_cast(bf16x8, a), __builtin_bit_cast(bf16x8, b), c, 0, 0, 0);
}
__device__ __forceinline__ float fast_tanh(float x) {
  x = fminf(fmaxf(x, -15.f), 15.f);
  float e = __expf(2.f * x);
  return (e - 1.f) * __builtin_amdgcn_rcpf(e + 1.f);
}

template<int T>
__device__ __forceinline__ void topk_insert(float (&v)[T], int (&ix)[T], float val, int idx) {
  if (val <= v[T-1]) return;
  v[T-1] = val; ix[T-1] = idx;
  #pragma unroll
  for (int j = T-1; j > 0; --j) {
    bool sw = v[j] > v[j-1];
    float tv = sw ? v[j] : v[j-1];  float uv = sw ? v[j-1] : v[j];
    int   ti = sw ? ix[j] : ix[j-1]; int  ui = sw ? ix[j-1] : ix[j];
    v[j-1] = tv; v[j] = uv; ix[j-1] = ti; ix[j] = ui;
  }
}

// ---------------- K0: query prep only (256 blocks) ----------------
__global__ __launch_bounds__(256) void k0_prep(const float* __restrict__ qfeat,
                                               float* __restrict__ qr,
                                               unsigned short* __restrict__ qf,
                                               float* __restrict__ qn) {
  int b = blockIdx.x, t = threadIdx.x;
  float s = 0.f;
  #pragma unroll
  for (int p = 0; p < 2; ++p) {
    int k = t + p*256;
    float v = qfeat[b*DD + k];
    v = v > 0.f ? v : 0.f;
    qr[b*DD + k] = v;
    qf[(((b>>4)*64 + (k>>3))*16 + (b&15))*8 + (k&7)] = f2bf(v);
    s += v*v;
  }
  __shared__ float red[4];
  #pragma unroll
  for (int st = 1; st < 64; st <<= 1) s += __shfl_xor(s, st, 64);
  if ((t & 63) == 0) red[t>>6] = s;
  __syncthreads();
  if (t == 0) qn[b] = sqrtf(red[0]+red[1]+red[2]+red[3]);
}

// ---------------- K1 (fused, 512 threads / 8 waves): 0..NB-1 coarse GEMM;
//                  NB..NB+31 qq GEMM; NB+32..NB+287 Wm frag ----------------
// k1 path: reg-staged bf16-LDS GEMM, 2-deep G prefetch. 8 waves, each wave owns
// 2 query n-tiles (acc[4][2] = 32 VGPR) -> ~100 VGPR -> more waves/CU for the
// inter-wave overlap that hides the per-iteration barrier drain (m114).
__global__ __launch_bounds__(512) void k1_fused(const float* __restrict__ keys,
                                                const unsigned short* __restrict__ qf,
                                                unsigned int* __restrict__ cand,
                                                const float* __restrict__ Wq,
                                                const float* __restrict__ bq,
                                                const float* __restrict__ bm,
                                                float* __restrict__ qq,
                                                const float* __restrict__ Wm,
                                                unsigned short* __restrict__ wmf) {
  __shared__ __align__(16) char shmem[16640];   // aliased: k1 8.4KB, qq 16KB
  int b = blockIdx.x, t = threadIdx.x;
  int w = t >> 6, l = t & 63, g = l >> 4, c = l & 15;
  const short8_t* qf8 = (const short8_t*)qf;

  if (b >= NB) {
    int bb = b - NB;
    if (bb >= 32) {
      // ---- Wm fragmenting path (256 blocks x 512 threads) ----
      int i = (bb - 32)*512 + t;   // i = d*256 + a, 131072 total
      int d = i >> 8, a = i & 255;
      wmf[(((a>>4)*64 + (d>>3))*16 + (a&15))*8 + (d&7)] = f2bf(Wm[i]);
      return;
    }
    // ---- k_qq path (32 blocks: 16 col-tiles x 2 row-groups; 8 row-tiles/block) ----
    unsigned short* wb = (unsigned short*)shmem;   // 16 KB
    int bn = bb & 15, rg = bb >> 4;
    #pragma unroll
    for (int i = 0; i < 16; ++i) {
      int d = i*32 + (t>>4); int a = t & 15;
      wb[((d>>3)*16 + a)*8 + (d&7)] = f2bf(Wq[d*AD + bn*16 + a]);
    }
    __syncthreads();
    const short8_t* wb8 = (const short8_t*)wb;
    f32x4 acc = (f32x4){0.f,0.f,0.f,0.f};
    int M = rg*8 + w;                        // this wave's 16-row tile (0..15)
    for (int kt = 0; kt < 16; ++kt) {
      short8_t bfr = wb8[(kt*4 + g)*16 + c];
      short8_t afr = qf8[(M*64 + kt*4 + g)*16 + c];
      acc = mfma_bf16(afr, bfr, acc);
    }
    int col = bn*16 + c;
    float bias = bq[col] + bm[col];
    #pragma unroll
    for (int r = 0; r < 4; ++r)
      qq[(M*16 + g*4 + r)*AD + col] = acc[r] + bias;
    return;
  }

  // ---- k1 path ----
  short8_t* Abf8 = (short8_t*)shmem;             // 8 KB
  float* invkn = (float*)(shmem + 8192);         // 256 B
  int kb0 = b*KB;

  f32x4 acc[4][2];   // [key m-tile][query n-tile (2 per wave)]
  #pragma unroll
  for (int m = 0; m < 4; ++m)
    #pragma unroll
    for (int n = 0; n < 2; ++n) acc[m][n] = (f32x4){0.f,0.f,0.f,0.f};

  // staging: thread t stages row r1 = t>>3, granule gb = t&7 (8 fp32 -> 8 bf16 = 16B)
  int r1 = t >> 3, gb = t & 7;
  int swz = gb ^ (r1 & 7);
  int row1 = kb0 + r1; row1 = row1 < NKEY ? row1 : NKEY-1;
  const float* src1 = keys + (size_t)row1*DD + gb*8;
  float ksq1 = 0.f;

  // prologue: B(0) [4 instr], then G(0) -> Ge [2], G(1) -> Go [2]
  short8_t Bcur[2][2];
  #pragma unroll
  for (int kt = 0; kt < 2; ++kt)
    #pragma unroll
    for (int n = 0; n < 2; ++n)
      Bcur[kt][n] = qf8[((w*2 + n)*64 + kt*4 + g)*16 + c];
  __builtin_amdgcn_sched_barrier(0);
  float4 Ge[2], Go[2];
  Ge[0] = *(const float4*)(src1);      Ge[1] = *(const float4*)(src1 + 4);
  __builtin_amdgcn_sched_barrier(0);
  Go[0] = *(const float4*)(src1 + 64); Go[1] = *(const float4*)(src1 + 68);

  auto body = [&](int ks8, float4 (&Gc)[2]) {
    // steady state outstanding at top: G(t)[2] + B(t)[4] + G(t+1)[2] = 8;
    // vmcnt(2) retires oldest 6 = G(t)+B(t), leaves G(t+1) in flight
    if (ks8 < 7) asm volatile("s_waitcnt vmcnt(2)" ::: "memory");
    else         asm volatile("s_waitcnt vmcnt(0)" ::: "memory");
    ksq1 += Gc[0].x*Gc[0].x + Gc[0].y*Gc[0].y + Gc[0].z*Gc[0].z + Gc[0].w*Gc[0].w
          + Gc[1].x*Gc[1].x + Gc[1].y*Gc[1].y + Gc[1].z*Gc[1].z + Gc[1].w*Gc[1].w;
    short8_t w1;
    w1[0] = (short)f2bf_n(Gc[0].x); w1[1] = (short)f2bf_n(Gc[0].y);
    w1[2] = (short)f2bf_n(Gc[0].z); w1[3] = (short)f2bf_n(Gc[0].w);
    w1[4] = (short)f2bf_n(Gc[1].x); w1[5] = (short)f2bf_n(Gc[1].y);
    w1[6] = (short)f2bf_n(Gc[1].z); w1[7] = (short)f2bf_n(Gc[1].w);
    __builtin_amdgcn_s_barrier();                       // prev-iter LDS reads done
    Abf8[r1*8 + swz] = w1;
    short8_t Bnxt[2][2];
    if (ks8 < 7) {
      #pragma unroll
      for (int kt = 0; kt < 2; ++kt)
        #pragma unroll
        for (int n = 0; n < 2; ++n)
          Bnxt[kt][n] = qf8[((w*2 + n)*64 + (ks8+1)*8 + kt*4 + g)*16 + c];
    }
    __builtin_amdgcn_sched_barrier(0);                  // pin B(t+1) before G(t+2)
    if (ks8 < 6) {
      Gc[0] = *(const float4*)(src1 + (ks8+2)*64);
      Gc[1] = *(const float4*)(src1 + (ks8+2)*64 + 4);
    }
    asm volatile("s_waitcnt lgkmcnt(0)" ::: "memory");  // own ds_write visible
    __builtin_amdgcn_s_barrier();
    __builtin_amdgcn_sched_barrier(0);
    int p = c & 7;
    #pragma unroll
    for (int kt = 0; kt < 2; ++kt) {
      #pragma unroll
      for (int m = 0; m < 4; ++m) {
        short8_t A = Abf8[(m*16 + c)*8 + ((kt*4 + g) ^ p)];
        #pragma unroll
        for (int n = 0; n < 2; ++n) acc[m][n] = mfma_bf16(A, Bcur[kt][n], acc[m][n]);
      }
    }
    if (ks8 < 7) {
      #pragma unroll
      for (int kt = 0; kt < 2; ++kt)
        #pragma unroll
        for (int n = 0; n < 2; ++n) Bcur[kt][n] = Bnxt[kt][n];
    }
  };

  #pragma unroll
  for (int ks8 = 0; ks8 < 8; ++ks8) {
    if (ks8 & 1) body(ks8, Go);
    else         body(ks8, Ge);
  }

  // norms: 8 gb-threads per row (consecutive t within a wave); reduce over bits 0..2
  ksq1 += __shfl_xor(ksq1, 1, 64); ksq1 += __shfl_xor(ksq1, 2, 64); ksq1 += __shfl_xor(ksq1, 4, 64);
  if ((t & 7) == 0) invkn[r1] = ksq1 > 0.f ? rsqrtf(ksq1) : 0.f;
  __syncthreads();

  float ikv[16];
  #pragma unroll
  for (int m = 0; m < 4; ++m)
    #pragma unroll
    for (int r = 0; r < 4; ++r) ikv[m*4 + r] = invkn[m*16 + g*4 + r];

  // per-lane branchless top-3 of the lane's 16 keys, per query column (2 per wave)
  #pragma unroll
  for (int n = 0; n < 2; ++n) {
    float v1 = -3.0e38f, v2 = -3.0e38f, v3 = -3.0e38f;
    int   i1 = 0, i2 = 0, i3 = 0;
    #pragma unroll
    for (int m = 0; m < 4; ++m)
      #pragma unroll
      for (int r = 0; r < 4; ++r) {
        int lid = m*16 + g*4 + r;
        bool valid = (kb0 + lid) < NKEY;
        float v = valid ? acc[m][n][r] * ikv[m*4 + r] : -3.0e38f;
        bool gt1 = v > v1, gt2 = v > v2, gt3 = v > v3;
        v3 = gt2 ? v2 : (gt3 ? v : v3);  i3 = gt2 ? i2 : (gt3 ? lid : i3);
        v2 = gt1 ? v1 : (gt2 ? v : v2);  i2 = gt1 ? i1 : (gt2 ? lid : i2);
        v1 = gt1 ? v  : v1;              i1 = gt1 ? lid : i1;
      }
    int q = w*32 + n*16 + c;
    unsigned int base = ((unsigned int)q*NB + (unsigned int)b)*12u + (unsigned int)g*3u;
    cand[base + 0] = ((unsigned int)__half_as_ushort(__float2half(v1)) << 16) | (unsigned int)i1;
    cand[base + 1] = ((unsigned int)__half_as_ushort(__float2half(v2)) << 16) | (unsigned int)i2;
    cand[base + 2] = ((unsigned int)__half_as_ushort(__float2half(v3)) << 16) | (unsigned int)i3;
  }
}

// ---------------- K2a: candidate reduce + EXACT fp32 rescore (8 blocks/query, 32 waves/CU) ----------------
__global__ __launch_bounds__(256) void k2a_reduce(const unsigned int* __restrict__ cand,
                                                  const float* __restrict__ qr,
                                                  const float* __restrict__ qn,
                                                  const float* __restrict__ keys,
                                                  float* __restrict__ wtopv,
                                                  int* __restrict__ wtopi) {
  int bid = blockIdx.x;
  int q = bid >> 3, p = bid & 7;
  int t = threadIdx.x, w = t >> 6, l = t & 63;
  const unsigned int* cq = cand + (size_t)q * CPQ;

  const int PER_PART = (CPQ + NPART - 1) / NPART;   // 2345
  const int PER_WAVE = (PER_PART + 3) / 4;          // 587
  int pbase = p * PER_PART;
  int start = pbase + w * PER_WAVE;
  int end   = pbase + PER_PART;
  if (start + PER_WAVE < end) end = start + PER_WAVE;
  if (end > CPQ) end = CPQ;

  float v[TLA]; int ix[TLA];
  #pragma unroll
  for (int j = 0; j < TLA; ++j) { v[j] = -INFINITY; ix[j] = -1; }
  for (int i = start + l; i < end; i += 64) {
    unsigned int pk = cq[i];
    float val = __half2float(__ushort_as_half((unsigned short)(pk >> 16)));
    int bb = i / 12;                       // compiler magic-mul
    int idx = (bb << 6) | (int)(pk & 63u);
    topk_insert<TLA>(v, ix, val, idx);
  }

  // wave merge: exact wave top-WTOP; winning index is wave-uniform -> keep in regs
  int idxs[WTOP];
  for (int it = 0; it < WTOP; ++it) {
    float bv = v[0]; int bx = ix[0]; int bl = l;
    #pragma unroll
    for (int sft = 1; sft < 64; sft <<= 1) {
      float ov = __shfl_xor(bv, sft, 64);
      int  oxx = __shfl_xor(bx, sft, 64);
      int  ol  = __shfl_xor(bl, sft, 64);
      bool take = (ov > bv) || (ov == bv && ol < bl);
      if (take) { bv = ov; bx = oxx; bl = ol; }
    }
    idxs[it] = bx;
    if (l == bl) {
      #pragma unroll
      for (int j = 0; j < TLA-1; ++j) { v[j] = v[j+1]; ix[j] = ix[j+1]; }
      v[TLA-1] = -INFINITY; ix[TLA-1] = -1;
    }
  }

  // exact fp32 rescore of this wave's 12 candidates (2-deep row pipeline; lane = 8-dim slice)
  const float4* q4 = (const float4*)(qr + (size_t)q*DD + l*8);
  float4 qa0 = q4[0], qa1 = q4[1];
  float qnv = qn[q];
  int obase = (q * NPART + p) * 4 * WTOP + w * WTOP;

  int nidx = idxs[0];
  const float4* kr = (const float4*)(keys + (size_t)((nidx < 0 || nidx >= NKEY) ? 0 : nidx)*DD + l*8);
  float4 k0v = kr[0], k1v = kr[1];
  for (int j = 0; j < WTOP; ++j) {
    int curidx = idxs[j];
    bool bad = (curidx < 0) || (curidx >= NKEY);
    float4 c0 = k0v, c1 = k1v;
    if (j + 1 < WTOP) {
      nidx = idxs[j+1];
      kr = (const float4*)(keys + (size_t)((nidx < 0 || nidx >= NKEY) ? 0 : nidx)*DD + l*8);
      k0v = kr[0]; k1v = kr[1];
    }
    float dot = qa0.x*c0.x + qa0.y*c0.y + qa0.z*c0.z + qa0.w*c0.w
              + qa1.x*c1.x + qa1.y*c1.y + qa1.z*c1.z + qa1.w*c1.w;
    float ks  = c0.x*c0.x + c0.y*c0.y + c0.z*c0.z + c0.w*c0.w
              + c1.x*c1.x + c1.y*c1.y + c1.z*c1.z + c1.w*c1.w;
    #pragma unroll
    for (int sft = 1; sft < 64; sft <<= 1) {
      dot += __shfl_xor(dot, sft, 64);
      ks  += __shfl_xor(ks,  sft, 64);
    }
    if (l == 0) {
      float den = fmaxf(qnv * sqrtf(ks), 1e-8f);
      wtopv[obase + j] = bad ? -1e30f : dot/den;
      wtopi[obase + j] = bad ? 0 : curidx;
    }
  }
}

// ---------------- K23ab (512 threads): top-32 select -> gather -> attention -> attf ----------------
__global__ __launch_bounds__(512) void k23ab(const float* __restrict__ wtopv,
                                             const int* __restrict__ wtopi,
                                             const float* __restrict__ keys,
                                             const float* __restrict__ qq,
                                             const unsigned short* __restrict__ wmf,
                                             const float* __restrict__ Ws,
                                             const float* __restrict__ bsc,
                                             unsigned short* __restrict__ attf) {
  int q = blockIdx.x, t = threadIdx.x, w = t >> 6, l = t & 63, g = l >> 4, c = l & 15;
  __shared__ float simx[NC2];
  __shared__ int   sidx[NC2];
  __shared__ int   fl[KSEL];
  __shared__ float qqb[256];
  __shared__ float wsl[256];
  __shared__ unsigned short knnb[32*520];
  __shared__ float spart[8][32];
  __shared__ float wexp[32];

  if (t < 256) {
    qqb[t] = qq[q*AD + t];
    wsl[t] = Ws[t];
  }
  for (int i = t; i < NC2; i += 512) {
    simx[i] = wtopv[q*NC2 + i];
    int idx = wtopi[q*NC2 + i];
    sidx[i] = (idx < 0 || idx >= NKEY) ? 0 : idx;
  }
  __syncthreads();

  // wave 0: exact top-32 of 384, tie-break value desc then index asc (lax.top_k)
  if (w == 0) {
    float a[6]; int id[6];
    #pragma unroll
    for (int j = 0; j < 6; ++j) { a[j] = simx[j*64 + l]; id[j] = sidx[j*64 + l]; }
    for (int it = 0; it < KSEL; ++it) {
      float bv = a[0]; int bx = id[0]; int bslot = 0;
      #pragma unroll
      for (int j = 1; j < 6; ++j) {
        bool take = (a[j] > bv) || (a[j] == bv && id[j] < bx);
        bv = take ? a[j] : bv; bx = take ? id[j] : bx; bslot = take ? j : bslot;
      }
      int bl = l;
      #pragma unroll
      for (int sft = 1; sft < 64; sft <<= 1) {
        float ov = __shfl_xor(bv, sft, 64);
        int  oxx = __shfl_xor(bx, sft, 64);
        int  ol  = __shfl_xor(bl, sft, 64);
        bool take = (ov > bv) || (ov == bv && oxx < bx);
        if (take) { bv = ov; bx = oxx; bl = ol; }
      }
      if (l == 0) fl[it] = bx;
      if (l == bl) {
        #pragma unroll
        for (int j = 0; j < 6; ++j) if (j == bslot) a[j] = -INFINITY;
      }
    }
  }
  __syncthreads();

  // gather knn (bf16): 4 rows per pass, 128 lanes x float4 per row
  #pragma unroll 4
  for (int rr = 0; rr < 32; rr += 4) {
    int r = rr + (t >> 7);
    int row = fl[r];
    int d4 = t & 127;
    float4 v = *(const float4*)(keys + (size_t)row*DD + d4*4);
    ushort4 h; h.x = f2bf_n(v.x); h.y = f2bf_n(v.y); h.z = f2bf_n(v.z); h.w = f2bf_n(v.w);
    *(ushort4*)&knnb[r*520 + d4*4] = h;
  }
  __syncthreads();

  // MFMA knn@Wm: 8 waves, each wave 2 A-col tiles (a = (w*2+n)*16 + c)
  f32x4 acc[2][2];
  #pragma unroll
  for (int m = 0; m < 2; ++m)
    #pragma unroll
    for (int n = 0; n < 2; ++n) acc[m][n] = (f32x4){0.f,0.f,0.f,0.f};
  const short8_t* wmf8 = (const short8_t*)wmf;
  for (int ks = 0; ks < 16; ++ks) {
    short8_t af[2], bf[2];
    #pragma unroll
    for (int m = 0; m < 2; ++m) af[m] = *(const short8_t*)&knnb[(m*16 + c)*520 + ks*32 + g*8];
    #pragma unroll
    for (int n = 0; n < 2; ++n) bf[n] = wmf8[((w*2 + n)*64 + ks*4 + g)*16 + c];
    #pragma unroll
    for (int m = 0; m < 2; ++m)
      #pragma unroll
      for (int n = 0; n < 2; ++n) acc[m][n] = mfma_bf16(af[m], bf[n], acc[m][n]);
  }

  float p[8] = {0.f,0.f,0.f,0.f,0.f,0.f,0.f,0.f};
  #pragma unroll
  for (int n = 0; n < 2; ++n) {
    int a = w*32 + n*16 + c;
    float qv = qqb[a], wv = wsl[a];
    #pragma unroll
    for (int m = 0; m < 2; ++m)
      #pragma unroll
      for (int r = 0; r < 4; ++r)
        p[m*4 + r] += fast_tanh(acc[m][n][r] + qv) * wv;
  }
  #pragma unroll
  for (int sft = 1; sft < 16; sft <<= 1)
    #pragma unroll
    for (int i = 0; i < 8; ++i) p[i] += __shfl_xor(p[i], sft, 64);
  if (c == 0) {
    #pragma unroll
    for (int m = 0; m < 2; ++m)
      #pragma unroll
      for (int r = 0; r < 4; ++r) spart[w][m*16 + g*4 + r] = p[m*4 + r];
  }
  __syncthreads();

  if (t < 32) {
    float s = bsc[0];
    #pragma unroll
    for (int ww = 0; ww < 8; ++ww) s += spart[ww][t];
    float mx = s;
    #pragma unroll
    for (int sft = 1; sft < 32; sft <<= 1) mx = fmaxf(mx, __shfl_xor(mx, sft, 64));
    float e = __expf(s - mx);
    float su = e;
    #pragma unroll
    for (int sft = 1; sft < 32; sft <<= 1) su += __shfl_xor(su, sft, 64);
    wexp[t] = e / su;
  }
  __syncthreads();

  {
    int d = t;   // 512 threads cover all 512 dims in one pass
    float s = 0.f;
    #pragma unroll
    for (int k = 0; k < 32; ++k) s += wexp[k] * bf2f(knnb[k*520 + d]);
    attf[(((q>>4)*64 + (d>>3))*16 + (q&15))*8 + (d&7)] = f2bf(s);
  }
}

// ---------------- K3b: out = [q, attended] @ Wc + bc  (28 blocks: 7 col-tiles x 4 row-groups) ----------------
__global__ __launch_bounds__(256) void k3b_cls(const float* __restrict__ Wc,
                                               const unsigned short* __restrict__ qf,
                                               const unsigned short* __restrict__ attf,
                                               const float* __restrict__ bc,
                                               float* __restrict__ out) {
  __shared__ unsigned short wb[128*16*8];   // 32 KB
  int bn = blockIdx.x % 7, rg = blockIdx.x / 7;
  int t = threadIdx.x;
  int w = t >> 6, l = t & 63, g = l >> 4, c = l & 15;
  #pragma unroll
  for (int i = 0; i < 64; ++i) {
    int d = i*16 + (t>>4); int a = t & 15;
    int col = bn*16 + a;
    float vv = (col < CD) ? Wc[d*CD + col] : 0.f;
    wb[((d>>3)*16 + a)*8 + (d&7)] = f2bf(vv);
  }
  __syncthreads();
  const short8_t* qf8 = (const short8_t*)qf;
  const short8_t* af8 = (const short8_t*)attf;
  const short8_t* wb8 = (const short8_t*)wb;
  int M = rg*4 + w;                         // this wave's 16-row tile (0..15)
  f32x4 acc = (f32x4){0.f,0.f,0.f,0.f};
  for (int kt = 0; kt < 32; ++kt) {
    short8_t bfr = wb8[(kt*4 + g)*16 + c];
    const short8_t* asrc = (kt < 16) ? qf8 : af8;
    int kbase = (kt & 15)*4 + g;
    short8_t afr = asrc[(M*64 + kbase)*16 + c];
    acc = mfma_bf16(afr, bfr, acc);
  }
  int col = bn*16 + c;
  if (col < CD) {
    float bias = bc[col];
    #pragma unroll
    for (int r = 0; r < 4; ++r)
      out[(M*16 + g*4 + r)*CD + col] = acc[r] + bias;
  }
}

// ---------------- launch ----------------
extern "C" void kernel_launch(void* const* d_in, const int* in_sizes, int n_in,
                              void* d_out, int out_size, void* d_ws, size_t ws_size,
                              hipStream_t stream) {
  const float* qfeat = (const float*)d_in[0];
  const float* keys  = (const float*)d_in[1];
  const float* Wq    = (const float*)d_in[2];
  const float* bq    = (const float*)d_in[3];
  const float* Wm    = (const float*)d_in[4];
  const float* bm    = (const float*)d_in[5];
  const float* Ws    = (const float*)d_in[6];
  const float* bsc   = (const float*)d_in[7];
  const float* Wc    = (const float*)d_in[8];
  const float* bc    = (const float*)d_in[9];
  float* out = (float*)d_out;

  char* ws = (char*)d_ws;
  unsigned short* qf   = (unsigned short*)(ws + 0);          // 262144 B
  float*          qr   = (float*)(ws + 262144);              // 524288 B
  float*          qn   = (float*)(ws + 786432);              // 1024 B
  unsigned short* wmf  = (unsigned short*)(ws + 787456);     // 262144 B
  float*          qq   = (float*)(ws + 1049600);             // 262144 B
  unsigned short* attf = (unsigned short*)(ws + 1311744);    // 262144 B
  float*          wtopv= (float*)(ws + 1573888);             // 393216 B
  int*            wtopi= (int*)(ws + 1967104);               // 393216 B
  unsigned int*   cand = (unsigned int*)(ws + 2360320);      // 19203072 B

  k0_prep   <<<BQ,       256, 0, stream>>>(qfeat, qr, qf, qn);
  k1_fused  <<<NB + 288, 512, 0, stream>>>(keys, qf, cand, Wq, bq, bm, qq, Wm, wmf);
  k2a_reduce<<<BQ*NPART, 256, 0, stream>>>(cand, qr, qn, keys, wtopv, wtopi);
  k23ab     <<<BQ,       512, 0, stream>>>(wtopv, wtopi, keys, qq, wmf, Ws, bsc, attf);
  k3b_cls   <<<28,       256, 0, stream>>>(Wc, qf, attf, bc, out);
}